// Round 10
// baseline (691.785 us; speedup 1.0000x reference)
//
#include <hip/hip_runtime.h>
#include <math.h>

#define NBATCH 8
#define NATOM  256
#define NP1    257
#define WROW   258
#define TOTALK 9261
#define KCAP   2560
#define KC     16
#define NB     16
#define UBW    244
#define BD     512
#define BDB    256

#define TWO_PI_D 6.283185307179586
#define DIAG_SUB 0.7978845608028654   /* 2/sqrt(2*pi) */

__device__ __constant__ int TI10[10] = {0,0,0,0,1,1,1,2,2,3};
__device__ __constant__ int TJ10[10] = {0,1,2,3,1,2,3,2,3,3};

struct GemmSh {
  int4   kn[KC];
  double kw[KC];
  double cI[KC][64], sI[KC][64];
  double cJ[KC][64], sJ[KC][64];
};

// HW fp64 atomic add (gfx90a+/gfx950); CAS fallback if builtin missing.
__device__ __forceinline__ void atomAddD(double* p, double v) {
#if defined(__has_builtin)
#if __has_builtin(__builtin_amdgcn_global_atomic_fadd_f64)
  __builtin_amdgcn_global_atomic_fadd_f64(p, v);
  return;
#endif
#endif
  unsigned long long* u = (unsigned long long*)p;
  unsigned long long old = *u, assumed;
  do {
    assumed = old;
    old = atomicCAS(u, assumed,
                    (unsigned long long)__double_as_longlong(
                        v + __longlong_as_double((long long)assumed)));
  } while (old != assumed);
}

__device__ __forceinline__ void classify2(const void* c0, const void* c1, const void* c2,
                                          const float*& chi, const int*& znum)
{
  const void* cands[3] = {c0, c1, c2};
  int got = 0;
  for (int i = 0; i < 3; i++) {
    unsigned uu = ((const unsigned*)cands[i])[0];
    if (uu == 0u) continue;                                      // batch
    else if (uu < 16u) { znum = (const int*)cands[i]; got |= 1; }// z in {1,6,7,8}
    else               { chi  = (const float*)cands[i]; got |= 2; }
  }
  if (got != 3) { chi = (const float*)c0; znum = (const int*)c1; }
}

// ---------------- K0 (grid 512): zero all A-planes at full chip write BW ----------
// (r9 zeroed from prep's 8 blocks: ~30us at 8-CU write BW. 512 blocks: ~3us.)
__global__ __launch_bounds__(256) void zero_planes(
    double* __restrict__ P0g, int nplanes)
{
  const size_t npair = (size_t)nplanes * NBATCH * ((NP1*WROW) >> 1);
  double2* Z = (double2*)P0g;   // planes are contiguous: [P0][P1][P2]
  const double2 z = make_double2(0.0, 0.0);
  for (size_t i = (size_t)blockIdx.x*256 + threadIdx.x; i < npair;
       i += (size_t)gridDim.x*256)
    Z[i] = z;
}

// ---------------- K1 (grid 8): trig tables + k-list + aug borders ----------------
__global__ __launch_bounds__(256) void prep(
    const float* __restrict__ pos, const float* __restrict__ cell,
    double2* __restrict__ Tg, int4* __restrict__ klist,
    double* __restrict__ kw, int* __restrict__ kcount,
    const void* __restrict__ c0, const void* __restrict__ c1, const void* __restrict__ c2,
    const float* __restrict__ syschg,
    double* __restrict__ P0g, int nplanes)
{
  const int b = blockIdx.x;
  const int tid = threadIdx.x;
  __shared__ double ivs[9];
  __shared__ double prefs;
  __shared__ int cnt;
  if (tid == 0) {
    double c[9];
#pragma unroll
    for (int i = 0; i < 9; i++) c[i] = (double)cell[b*9+i];
    double det = c[0]*(c[4]*c[8]-c[5]*c[7]) - c[1]*(c[3]*c[8]-c[5]*c[6])
               + c[2]*(c[3]*c[7]-c[4]*c[6]);
    double idet = 1.0/det;
    ivs[0]=(c[4]*c[8]-c[5]*c[7])*idet; ivs[1]=(c[2]*c[7]-c[1]*c[8])*idet; ivs[2]=(c[1]*c[5]-c[2]*c[4])*idet;
    ivs[3]=(c[5]*c[6]-c[3]*c[8])*idet; ivs[4]=(c[0]*c[8]-c[2]*c[6])*idet; ivs[5]=(c[2]*c[3]-c[0]*c[5])*idet;
    ivs[6]=(c[3]*c[7]-c[4]*c[6])*idet; ivs[7]=(c[1]*c[6]-c[0]*c[7])*idet; ivs[8]=(c[0]*c[4]-c[1]*c[3])*idet;
    prefs = 2.0*TWO_PI_D/fabs(det);
    cnt = 0;
  }
  __syncthreads();
  {
    const int a = tid;
    double x = (double)pos[((size_t)b*NATOM+a)*3+0];
    double y = (double)pos[((size_t)b*NATOM+a)*3+1];
    double z = (double)pos[((size_t)b*NATOM+a)*3+2];
    double u[3];
    u[0] = TWO_PI_D*(ivs[0]*x + ivs[3]*y + ivs[6]*z);
    u[1] = TWO_PI_D*(ivs[1]*x + ivs[4]*y + ivs[7]*z);
    u[2] = TWO_PI_D*(ivs[2]*x + ivs[5]*y + ivs[8]*z);
#pragma unroll
    for (int d = 0; d < 3; d++) {
      double2* T = Tg + (size_t)((b*3 + d)*21)*256;
      double c1 = cos(u[d]);
      double s1 = sin(u[d]);
      T[10*256 + a] = make_double2(1.0, 0.0);
      T[11*256 + a] = make_double2(c1,  s1);
      T[ 9*256 + a] = make_double2(c1, -s1);
      double cp = c1, sp = s1;
      for (int n = 2; n <= 10; n++) {
        double cn = cp*c1 - sp*s1;
        double sn = sp*c1 + cp*s1;
        cp = cn; sp = sn;
        T[(10+n)*256 + a] = make_double2(cp,  sp);
        T[(10-n)*256 + a] = make_double2(cp, -sp);
      }
    }
  }
  const double ksqmax = (TWO_PI_D/1.5)*(TWO_PI_D/1.5);
  for (int m = tid; m < TOTALK; m += 256) {
    int n1 = m/441 - 10;
    int n2 = (m/21)%21 - 10;
    int n3 = m%21 - 10;
    bool half = (n1 > 0) || (n1 == 0 && (n2 > 0 || (n2 == 0 && n3 > 0)));
    if (!half) continue;
    double d1 = n1, d2 = n2, d3 = n3;
    double kx = TWO_PI_D*(ivs[0]*d1 + ivs[1]*d2 + ivs[2]*d3);
    double ky = TWO_PI_D*(ivs[3]*d1 + ivs[4]*d2 + ivs[5]*d3);
    double kz = TWO_PI_D*(ivs[6]*d1 + ivs[7]*d2 + ivs[8]*d3);
    double k2 = kx*kx + ky*ky + kz*kz;
    if (k2 > 1e-10 && k2 < ksqmax) {
      double w = 2.0 * prefs * exp(-0.5*k2) / k2;
      int slot = atomicAdd(&cnt, 1);
      klist[b*KCAP + slot] = make_int4(n1, n2, n3, 0);
      kw[b*KCAP + slot] = w;
    }
  }
  __syncthreads();   // k-list complete before kcount
  // aug borders (plane0 real values; planes 1,2 zeroed by zero_planes)
  {
    const float* chi = nullptr; const int* znum = nullptr;
    classify2(c0, c1, c2, chi, znum);
    double* P0b = P0g + (size_t)b*NP1*WROW;
    for (int i = tid; i < NATOM; i += 256) {
      P0b[(size_t)NATOM*WROW + i] = 1.0;
      P0b[(size_t)i*WROW + NATOM] = 1.0;
      P0b[(size_t)i*WROW + 257]   = -(double)chi[b*NATOM + i];
    }
    if (tid == 0) {
      P0b[(size_t)NATOM*WROW + NATOM] = 0.0;
      P0b[(size_t)NATOM*WROW + 257]   = (double)syschg[b]*sqrt(90.0474);
      kcount[b] = cnt;
    }
  }
}

// ---------------- fp64 tile GEMM, ACCUMULATING into aug-geometry plane ----------
__device__ void gemm_tile(int b, int ti, int tj, int tid,
                          const double2* __restrict__ Tg,
                          const int4* __restrict__ klist,
                          const double* __restrict__ kw, int ks, int ke,
                          double* __restrict__ Ab, bool mirror, GemmSh& S)
{
  const int tx = tid & 15, ty = tid >> 4;
  const int ro = ty << 2, co = tx << 2;
  double acc[16];
#pragma unroll
  for (int i = 0; i < 16; i++) acc[i] = 0.0;

  for (int k0 = ks; k0 < ke; k0 += KC) {
    if (tid < KC) {
      int kk = k0 + tid;
      if (kk < ke) { S.kn[tid] = klist[b*KCAP + kk]; S.kw[tid] = kw[b*KCAP + kk]; }
      else         { S.kn[tid] = make_int4(0,0,0,0); S.kw[tid] = 0.0; }
    }
    __syncthreads();
#pragma unroll
    for (int p = 0; p < 8; p++) {
      int idx = p*256 + tid;
      int a    = idx & 63;
      int kk   = (idx >> 6) & (KC-1);
      int side = idx >> 10;
      int atom = ((side == 0) ? ti : tj) + a;
      int4 nn = S.kn[kk];
      double2 t1 = Tg[(size_t)((b*3+0)*21 + (nn.x+10))*256 + atom];
      double2 t2 = Tg[(size_t)((b*3+1)*21 + (nn.y+10))*256 + atom];
      double2 t3 = Tg[(size_t)((b*3+2)*21 + (nn.z+10))*256 + atom];
      double ex = t1.x*t2.x - t1.y*t2.y;
      double ey = t1.x*t2.y + t1.y*t2.x;
      double cx = ex*t3.x - ey*t3.y;
      double cy = ex*t3.y + ey*t3.x;
      if (side == 0) { double w = S.kw[kk]; S.cI[kk][a] = w*cx; S.sI[kk][a] = w*cy; }
      else           { S.cJ[kk][a] = cx; S.sJ[kk][a] = cy; }
    }
    __syncthreads();
#pragma unroll
    for (int kk = 0; kk < KC; kk++) {
      double ci[4], si[4], cj[4], sj[4];
#pragma unroll
      for (int r = 0; r < 2; r++) {
        double2 v0 = *(const double2*)&S.cI[kk][ro + 2*r];
        ci[2*r] = v0.x; ci[2*r+1] = v0.y;
        double2 v1 = *(const double2*)&S.sI[kk][ro + 2*r];
        si[2*r] = v1.x; si[2*r+1] = v1.y;
        double2 v2 = *(const double2*)&S.cJ[kk][co + 2*r];
        cj[2*r] = v2.x; cj[2*r+1] = v2.y;
        double2 v3 = *(const double2*)&S.sJ[kk][co + 2*r];
        sj[2*r] = v3.x; sj[2*r+1] = v3.y;
      }
#pragma unroll
      for (int r = 0; r < 4; r++)
#pragma unroll
        for (int c = 0; c < 4; c++)
          acc[r*4+c] += ci[r]*cj[c] + si[r]*sj[c];
    }
    __syncthreads();
  }
#pragma unroll
  for (int r = 0; r < 4; r++) {
#pragma unroll
    for (int c = 0; c < 4; c++) {
      int gr = ti + ro + r, gc = tj + co + c;
      double v = acc[r*4+c];
      atomAddD(&Ab[(size_t)gr*WROW + gc], v);
      if (mirror && ti != tj) atomAddD(&Ab[(size_t)gc*WROW + gr], v);
    }
  }
}

__device__ __forceinline__ double* plane_sel(double* P0, double* P1, double* P2, int s) {
  return (s == 0) ? P0 : ((s == 1) ? P1 : P2);
}

// ---------------- K2 (grid 320*nplanes): tiles x batches x 4*nplanes k-segments ----
// 12-way k-split (at nplanes=3) -> 960 blocks => ~4 blocks/CU co-resident: r9's
// 6-way split gave -56us; the blocks are staging-latency + barrier bound, so
// doubling co-residency again should roughly halve build_A wall once more.
// Segments accumulate into their plane via HW fp64 atomics (planes pre-zeroed).
__global__ __launch_bounds__(256) void build_A_gemm(
    const double2* __restrict__ Tg, const int4* __restrict__ klist,
    const double* __restrict__ kw, const int* __restrict__ kcount,
    double* __restrict__ P0g, double* __restrict__ P1g, double* __restrict__ P2g,
    int nplanes)
{
  __shared__ GemmSh S;
  const int nseg = 4*nplanes;
  const int u = blockIdx.x;
  const int seg = u / 80;
  const int r = u - seg*80;
  const int b = r / 10;
  const int t = r - b*10;
  const int s = seg % nplanes;
  const int cnt = kcount[b];
  const int ks = (int)((long long)cnt * seg / nseg);
  const int ke = (int)((long long)cnt * (seg+1) / nseg);
  double* Ab = plane_sel(P0g, P1g, P2g, s) + (size_t)b*NP1*WROW;
  gemm_tile(b, TI10[t]*64, TJ10[t]*64, threadIdx.x, Tg, klist, kw, ks, ke, Ab, true, S);
}

// ---------------- K4a (grid 8, block 512): no-pivot blocked LU factor, NB=16 ----
// r7-proven structure (341us, 92 VGPR, no spill) — byte-identical to r9.
__global__ __launch_bounds__(BD, 2) void solve_factor(
    double* __restrict__ P0g, const double* __restrict__ P1g, const double* __restrict__ P2g,
    int nplanes,
    const void* __restrict__ c0, const void* __restrict__ c1, const void* __restrict__ c2,
    const float* __restrict__ Jraw)
{
  const int b = blockIdx.x;
  const int tid = threadIdx.x;
  double* Pb = P0g + (size_t)b*NP1*WROW;
  const double* Qb = P1g + (size_t)b*NP1*WROW;
  const double* Rb = P2g + (size_t)b*NP1*WROW;
  const bool two   = (nplanes > 1);
  const bool three = (nplanes > 2);

  __shared__ __align__(16) double pan[NP1+4][NB+2];  // +4 rows: OOB-read pad for 2-row tiles
  __shared__ double dnv[NB];
  __shared__ __align__(16) double Ub[NB][UBW];

  const float* chi = nullptr; const int* znum = nullptr;
  classify2(c0, c1, c2, chi, znum);
  const float J0 = Jraw[0], J1 = Jraw[1], J2 = Jraw[2], J3 = Jraw[3];

  for (int p0 = 0; p0 < NP1; p0 += NB) {
    const int pw  = (NB < NP1 - p0) ? NB : (NP1 - p0);   // 16 x16 panels, then 1
    const int nr  = NP1 - p0;
    const int nrt = nr - pw;
    const int tc0 = p0 + pw;
    const int tc  = WROW - tc0;
    const bool first = (p0 == 0);
    // ---- 1. panel load (first panel: fused plane-sum + J-diag) ----
    for (int idx = tid; idx < nr*pw; idx += BD) {
      int r, c;
      if (pw == NB) { r = idx >> 4; c = idx & 15; } else { r = idx; c = 0; }
      double v;
      if (first) {
        size_t a = (size_t)r*WROW + c;
        v = Pb[a];
        if (two)   v += Qb[a];
        if (three) v += Rb[a];
        if (r == c) {
          int z = znum[b*NATOM + r];
          float Jr = (z == 1) ? J0 : (z == 6) ? J1 : (z == 7) ? J2 : J3;
          v += (double)Jr*(double)Jr - DIAG_SUB;
        }
      } else {
        v = Pb[(size_t)(p0+r)*WROW + p0 + c];
      }
      pan[r][c] = v;
    }
    __syncthreads();
    // ---- 2. diag 16x16 factor: 16 lanes, rows in registers, shfl-on-demand ----
    if (pw == NB) {
      if (tid < NB) {
        double v[NB];
#pragma unroll
        for (int c = 0; c < NB; c++) v[c] = pan[tid][c];
#pragma unroll
        for (int c = 0; c < NB; c++) {
          double piv = __shfl(v[c], c);
          double dinv = 1.0 / piv;
          if (tid == c) dnv[c] = dinv;
          double f = v[c] * dinv;          // only meaningful for tid > c
#pragma unroll
          for (int cc = 0; cc < NB; cc++) {
            if (cc > c) {
              double ucc = __shfl(v[cc], c);
              if (tid > c) v[cc] -= f * ucc;
            }
          }
          if (tid > c) v[c] = f;
        }
#pragma unroll
        for (int c = 0; c < NB; c++) pan[tid][c] = v[c];
      }
    }
    __syncthreads();
    // ---- 3+4. L21 row-TRSM || U12 col-TRSM || diag write-back (all read-only on
    //           the factored diag block; writes disjoint). nrt<=241<256, tc<=242. ----
    if (pw == NB) {
      if (tid < nrt) {
        const int r = NB + tid;
        double w[NB];
#pragma unroll
        for (int c = 0; c < NB; c++) w[c] = pan[r][c];
#pragma unroll
        for (int c = 0; c < NB; c++) {
          double s = w[c];
#pragma unroll
          for (int c2 = 0; c2 < NB; c2++) if (c2 < c) s -= w[c2] * pan[c2][c];
          w[c] = s * dnv[c];
        }
#pragma unroll
        for (int c = 0; c < NB; c++) pan[r][c] = w[c];
      } else if (tid >= 256 && tid < 256 + tc) {
        const int j = tc0 + (tid - 256);
        double v[NB];
#pragma unroll
        for (int c = 0; c < NB; c++) {
          size_t a = (size_t)(p0+c)*WROW + j;
          double t = Pb[a];
          if (first) {
            if (two)   t += Qb[a];
            if (three) t += Rb[a];
          }
          v[c] = t;
        }
#pragma unroll
        for (int c = 0; c < NB; c++)
#pragma unroll
          for (int r2 = 0; r2 < NB; r2++) if (r2 > c) v[r2] -= pan[r2][c]*v[c];
#pragma unroll
        for (int c = 0; c < NB; c++) {
          Pb[(size_t)(p0+c)*WROW + j] = v[c];
          Ub[c][tid - 256] = v[c];
        }
      } else {
        // U11/L11 write-back for the backsolve (reads-only pan)
        const int nh = (256 - nrt) + (256 - tc);
        int hid = (tid < 256) ? (tid - nrt) : ((256 - nrt) + (tid - 256 - tc));
        for (int idx = hid; idx < NB*NB; idx += nh) {
          int r2 = idx >> 4, c2 = idx & 15;
          Pb[(size_t)(p0+r2)*WROW + p0 + c2] = pan[r2][c2];
        }
      }
    } else {
      if (tid == 0) Pb[(size_t)p0*WROW + p0] = pan[0][0];
    }
    __syncthreads();
    // ---- 5. trailing rank-16 update: 128 col-pair lanes x 4 row-groups x 2 rows.
    //         va/vb REGISTER-resident; next row-pair prefetched into regs before
    //         the FMA loop (hides L2 latency under FMA issue). ----
    if (pw == NB) {
      const int jp   = tid & 127;
      const int rowg = tid >> 7;        // 0..3, wave-uniform
      const int j0 = 2*jp;
      if (j0 < tc && nrt > 0) {
        double va[NB], vb[NB];
#pragma unroll
        for (int c = 0; c < NB; c++) {
          double2 u = *(const double2*)&Ub[c][j0];
          va[c] = u.x; vb[c] = u.y;
        }
        auto loadrow = [&](int rr, double2& x0, double2& x1) {
          x0 = make_double2(0.0, 0.0); x1 = x0;
          if (rr < nrt) {
            const int row0 = tc0 + rr;
            const size_t ad = (size_t)row0*WROW + tc0 + j0;
            x0 = *(const double2*)&Pb[ad];
            if (rr + 1 < nrt) x1 = *(const double2*)&Pb[ad + WROW];
            if (first) {
              if (two) {
                double2 q0 = *(const double2*)&Qb[ad]; x0.x += q0.x; x0.y += q0.y;
                if (rr + 1 < nrt) { double2 q1 = *(const double2*)&Qb[ad + WROW]; x1.x += q1.x; x1.y += q1.y; }
              }
              if (three) {
                double2 r0v = *(const double2*)&Rb[ad]; x0.x += r0v.x; x0.y += r0v.y;
                if (rr + 1 < nrt) { double2 r1v = *(const double2*)&Rb[ad + WROW]; x1.x += r1v.x; x1.y += r1v.y; }
              }
              if (rr == j0) {             // rr even == j0 even: diag hits are
                if (row0 < NATOM) {       // (rr,j0)->x0.x and (rr+1,j1)->x1.y
                  int z = znum[b*NATOM + row0];
                  float Jr = (z == 1) ? J0 : (z == 6) ? J1 : (z == 7) ? J2 : J3;
                  x0.x += (double)Jr*(double)Jr - DIAG_SUB;
                }
                if (rr + 1 < nrt && row0 + 1 < NATOM) {
                  int z = znum[b*NATOM + row0 + 1];
                  float Jr = (z == 1) ? J0 : (z == 6) ? J1 : (z == 7) ? J2 : J3;
                  x1.y += (double)Jr*(double)Jr - DIAG_SUB;
                }
              }
            }
          }
        };
        int rr = 2*rowg;
        double2 a0, a1;
        loadrow(rr, a0, a1);
        while (rr < nrt) {
          const int rn = rr + 8;
          double2 n0, n1;
          loadrow(rn, n0, n1);             // prefetch next iteration's rows
          const double* pr0 = pan[NB + rr];
          const double* pr1 = pan[NB + rr + 1];   // padded row when rr+1==nrt
#pragma unroll
          for (int m = 0; m < NB/2; m++) {
            double2 l0 = *(const double2*)&pr0[2*m];
            double2 l1 = *(const double2*)&pr1[2*m];
            a0.x -= l0.x*va[2*m] + l0.y*va[2*m+1];
            a0.y -= l0.x*vb[2*m] + l0.y*vb[2*m+1];
            a1.x -= l1.x*va[2*m] + l1.y*va[2*m+1];
            a1.y -= l1.x*vb[2*m] + l1.y*vb[2*m+1];
          }
          const size_t ad = (size_t)(tc0+rr)*WROW + tc0 + j0;
          *(double2*)&Pb[ad] = a0;
          if (rr + 1 < nrt) *(double2*)&Pb[ad + WROW] = a1;
          a0 = n0; a1 = n1;
          rr = rn;
        }
      }
    }
    __syncthreads();
  }
}

// ---------------- K4b (grid 8, block 256): backsolve + outputs ----------------
__global__ __launch_bounds__(BDB) void solve_back(
    double* __restrict__ P0g,
    const void* __restrict__ c0, const void* __restrict__ c1, const void* __restrict__ c2,
    const float* __restrict__ Jraw, const float* __restrict__ syschg,
    float* __restrict__ out)
{
  const int b = blockIdx.x;
  const int tid = threadIdx.x;
  double* Pb = P0g + (size_t)b*NP1*WROW;

  __shared__ double panb[NB][NB+1];
  __shared__ double xs[NP1];
  __shared__ double red[BDB];

  const float* chi = nullptr; const int* znum = nullptr;
  classify2(c0, c1, c2, chi, znum);
  const double rhsN = (double)syschg[b] * sqrt(90.0474);
  const float J0 = Jraw[0], J1 = Jraw[1], J2 = Jraw[2], J3 = Jraw[3];

  for (int r = tid; r < NP1; r += BDB) xs[r] = Pb[(size_t)r*WROW + 257];
  __syncthreads();
  for (int pb0 = 256; pb0 >= 0; pb0 -= NB) {
    const int w = (pb0 == 256) ? 1 : NB;
    if (w == NB) {
      {
        const int i = tid >> 4, c = tid & 15;
        panb[i][c] = Pb[(size_t)(pb0+i)*WROW + pb0 + c];
      }
      __syncthreads();
      if (tid < NB) {
        double u[NB];
#pragma unroll
        for (int c = 0; c < NB; c++) u[c] = panb[tid][c];
        double y  = xs[pb0 + tid];
        double di = 1.0 / panb[tid][tid];   // direct LDS read, no dynamic reg index
        double xr = 0.0;
#pragma unroll
        for (int i = NB-1; i >= 0; i--) {
          double xi = y * di;            // only lane i's value is consumed
          xi = __shfl(xi, i);
          if (tid == i) xr = xi;
          if (tid < i)  y -= u[i] * xi;
        }
        xs[pb0 + tid] = xr;
      }
    } else {
      if (tid == 0) xs[256] = xs[256] / Pb[(size_t)256*WROW + 256];
    }
    __syncthreads();
    if (tid < pb0) {
      const double* rowp = &Pb[(size_t)tid*WROW + pb0];
      double s = 0.0;
      for (int c = 0; c < w; c++) s += rowp[c]*xs[pb0+c];
      xs[tid] -= s;
    }
    __syncthreads();
  }

  // ---- outputs: q + residual-identity energy ----
  out[b*NATOM + tid] = (float)xs[tid];
  const double lam = xs[NATOM];
  double q  = xs[tid];
  double ch = (double)chi[b*NATOM + tid];
  int z = znum[b*NATOM + tid];
  float Jr = (z == 1) ? J0 : (z == 6) ? J1 : (z == 7) ? J2 : J3;
  red[tid] = q*ch + (double)Jr*(double)Jr*q*q;
  __syncthreads();
  for (int st = BDB/2; st > 0; st >>= 1) {
    if (tid < st) red[tid] += red[tid + st];
    __syncthreads();
  }
  if (tid == 0)
    out[NBATCH*NATOM + b] = (float)(-0.5*(red[0] + lam*rhsN));
}

// ---------------- host launch ----------------
extern "C" void kernel_launch(void* const* d_in, const int* in_sizes, int n_in,
                              void* d_out, int out_size, void* d_ws, size_t ws_size,
                              hipStream_t stream)
{
  int iPos=-1, iCell=-1, iJ=-1, iQ=-1, cand[3]={-1,-1,-1}, nc=0;
  for (int i = 0; i < n_in; i++) {
    int s = in_sizes[i];
    if      (s == 6144) iPos  = i;
    else if (s == 72)   iCell = i;
    else if (s == 4)    iJ    = i;
    else if (s == 8)    iQ    = i;
    else if (s == 2048 && nc < 3) cand[nc++] = i;
  }
  if (!(iPos>=0 && iCell>=0 && iJ>=0 && iQ>=0 && nc>=2)) {
    iPos=iCell=iJ=iQ=-1; nc=0; cand[0]=cand[1]=cand[2]=-1;
    for (int i = 0; i < n_in; i++) {
      int s = in_sizes[i];
      if      (s == 24576) iPos  = i;
      else if (s == 288)   iCell = i;
      else if (s == 16)    iJ    = i;
      else if (s == 32)    iQ    = i;
      else if (s == 8192 && nc < 3) cand[nc++] = i;
    }
  }
  if (!(iPos>=0 && iCell>=0 && iJ>=0 && iQ>=0 && nc>=2)) {
    iPos=0; iCell=1; iJ=3; iQ=4; cand[0]=2; cand[1]=5; cand[2]=6; nc=3;
  }
  if (nc == 2) cand[2] = cand[1];

  const float* pos  = (const float*)d_in[iPos];
  const float* cell = (const float*)d_in[iCell];
  const float* Jraw = (const float*)d_in[iJ];
  const float* sysq = (const float*)d_in[iQ];
  const void*  c0   = d_in[cand[0]];
  const void*  c1   = d_in[cand[1]];
  const void*  c2   = d_in[cand[2]];
  float* out = (float*)d_out;

  // ws: [plane0][plane1][plane2][Tg][klist][kw][kcount]
  const size_t planeB = (size_t)NBATCH*NP1*WROW*sizeof(double);  // 4,243,584
  const size_t tgB = 2064384, klB = 327680, kwB = 163840;
  const size_t trigAll = tgB + klB + kwB + 64;
  int nplanes = (ws_size >= 3*planeB + trigAll) ? 3 :
                ((ws_size >= 2*planeB + trigAll) ? 2 : 1);

  char* ws = (char*)d_ws;
  double*  P0g = (double*)ws;
  double*  P1g = (nplanes > 1) ? (double*)(ws + planeB)   : P0g;
  double*  P2g = (nplanes > 2) ? (double*)(ws + 2*planeB) : P1g;
  char* trigBase = ws + (size_t)nplanes*planeB;
  double2* Tg     = (double2*)trigBase;
  int4*    klist  = (int4*)  (trigBase + tgB);
  double*  kwa    = (double*)(trigBase + tgB + klB);
  int*     kcount = (int*)   (trigBase + tgB + klB + kwB);

  hipLaunchKernelGGL(zero_planes,  dim3(512),           dim3(256), 0, stream,
                     P0g, nplanes);
  hipLaunchKernelGGL(prep,         dim3(NBATCH),        dim3(256), 0, stream,
                     pos, cell, Tg, klist, kwa, kcount, c0, c1, c2, sysq,
                     P0g, nplanes);
  hipLaunchKernelGGL(build_A_gemm, dim3(320*nplanes),   dim3(256), 0, stream,
                     Tg, klist, kwa, kcount, P0g, P1g, P2g, nplanes);
  hipLaunchKernelGGL(solve_factor, dim3(NBATCH),        dim3(BD),  0, stream,
                     P0g, P1g, P2g, nplanes, c0, c1, c2, Jraw);
  hipLaunchKernelGGL(solve_back,   dim3(NBATCH),        dim3(BDB), 0, stream,
                     P0g, c0, c1, c2, Jraw, sysq, out);
}

// Round 11
// 625.616 us; speedup vs baseline: 1.1058x; 1.1058x over previous
//
#include <hip/hip_runtime.h>
#include <math.h>

#define NBATCH 8
#define NATOM  256
#define NP1    257
#define WROW   258
#define TOTALK 9261
#define KCAP   2560
#define KC     16
#define NB     16
#define UBW    244
#define BDF    768
#define BDB    256

#define TWO_PI_D 6.283185307179586
#define DIAG_SUB 0.7978845608028654   /* 2/sqrt(2*pi) */

__device__ __constant__ int TI10[10] = {0,0,0,0,1,1,1,2,2,3};
__device__ __constant__ int TJ10[10] = {0,1,2,3,1,2,3,2,3,3};

struct GemmSh {
  int4   kn[KC];
  double kw[KC];
  double cI[KC][64], sI[KC][64];
  double cJ[KC][64], sJ[KC][64];
};

// HW fp64 atomic add (gfx90a+/gfx950); CAS fallback if builtin missing.
__device__ __forceinline__ void atomAddD(double* p, double v) {
#if defined(__has_builtin)
#if __has_builtin(__builtin_amdgcn_global_atomic_fadd_f64)
  __builtin_amdgcn_global_atomic_fadd_f64(p, v);
  return;
#endif
#endif
  unsigned long long* u = (unsigned long long*)p;
  unsigned long long old = *u, assumed;
  do {
    assumed = old;
    old = atomicCAS(u, assumed,
                    (unsigned long long)__double_as_longlong(
                        v + __longlong_as_double((long long)assumed)));
  } while (old != assumed);
}

__device__ __forceinline__ void classify2(const void* c0, const void* c1, const void* c2,
                                          const float*& chi, const int*& znum)
{
  const void* cands[3] = {c0, c1, c2};
  int got = 0;
  for (int i = 0; i < 3; i++) {
    unsigned uu = ((const unsigned*)cands[i])[0];
    if (uu == 0u) continue;                                      // batch
    else if (uu < 16u) { znum = (const int*)cands[i]; got |= 1; }// z in {1,6,7,8}
    else               { chi  = (const float*)cands[i]; got |= 2; }
  }
  if (got != 3) { chi = (const float*)c0; znum = (const int*)c1; }
}

// ---------------- K0 (grid 512): zero all A-planes at full chip write BW ----------
__global__ __launch_bounds__(256) void zero_planes(
    double* __restrict__ P0g, int nplanes)
{
  const size_t npair = (size_t)nplanes * NBATCH * ((NP1*WROW) >> 1);
  double2* Z = (double2*)P0g;   // planes are contiguous: [P0][P1][P2]
  const double2 z = make_double2(0.0, 0.0);
  for (size_t i = (size_t)blockIdx.x*256 + threadIdx.x; i < npair;
       i += (size_t)gridDim.x*256)
    Z[i] = z;
}

// ---------------- K1 (grid 8): trig tables + k-list + aug borders ----------------
__global__ __launch_bounds__(256) void prep(
    const float* __restrict__ pos, const float* __restrict__ cell,
    double2* __restrict__ Tg, int4* __restrict__ klist,
    double* __restrict__ kw, int* __restrict__ kcount,
    const void* __restrict__ c0, const void* __restrict__ c1, const void* __restrict__ c2,
    const float* __restrict__ syschg,
    double* __restrict__ P0g, int nplanes)
{
  const int b = blockIdx.x;
  const int tid = threadIdx.x;
  __shared__ double ivs[9];
  __shared__ double prefs;
  __shared__ int cnt;
  if (tid == 0) {
    double c[9];
#pragma unroll
    for (int i = 0; i < 9; i++) c[i] = (double)cell[b*9+i];
    double det = c[0]*(c[4]*c[8]-c[5]*c[7]) - c[1]*(c[3]*c[8]-c[5]*c[6])
               + c[2]*(c[3]*c[7]-c[4]*c[6]);
    double idet = 1.0/det;
    ivs[0]=(c[4]*c[8]-c[5]*c[7])*idet; ivs[1]=(c[2]*c[7]-c[1]*c[8])*idet; ivs[2]=(c[1]*c[5]-c[2]*c[4])*idet;
    ivs[3]=(c[5]*c[6]-c[3]*c[8])*idet; ivs[4]=(c[0]*c[8]-c[2]*c[6])*idet; ivs[5]=(c[2]*c[3]-c[0]*c[5])*idet;
    ivs[6]=(c[3]*c[7]-c[4]*c[6])*idet; ivs[7]=(c[1]*c[6]-c[0]*c[7])*idet; ivs[8]=(c[0]*c[4]-c[1]*c[3])*idet;
    prefs = 2.0*TWO_PI_D/fabs(det);
    cnt = 0;
  }
  __syncthreads();
  {
    const int a = tid;
    double x = (double)pos[((size_t)b*NATOM+a)*3+0];
    double y = (double)pos[((size_t)b*NATOM+a)*3+1];
    double z = (double)pos[((size_t)b*NATOM+a)*3+2];
    double u[3];
    u[0] = TWO_PI_D*(ivs[0]*x + ivs[3]*y + ivs[6]*z);
    u[1] = TWO_PI_D*(ivs[1]*x + ivs[4]*y + ivs[7]*z);
    u[2] = TWO_PI_D*(ivs[2]*x + ivs[5]*y + ivs[8]*z);
#pragma unroll
    for (int d = 0; d < 3; d++) {
      double2* T = Tg + (size_t)((b*3 + d)*21)*256;
      double c1 = cos(u[d]);
      double s1 = sin(u[d]);
      T[10*256 + a] = make_double2(1.0, 0.0);
      T[11*256 + a] = make_double2(c1,  s1);
      T[ 9*256 + a] = make_double2(c1, -s1);
      double cp = c1, sp = s1;
      for (int n = 2; n <= 10; n++) {
        double cn = cp*c1 - sp*s1;
        double sn = sp*c1 + cp*s1;
        cp = cn; sp = sn;
        T[(10+n)*256 + a] = make_double2(cp,  sp);
        T[(10-n)*256 + a] = make_double2(cp, -sp);
      }
    }
  }
  const double ksqmax = (TWO_PI_D/1.5)*(TWO_PI_D/1.5);
  for (int m = tid; m < TOTALK; m += 256) {
    int n1 = m/441 - 10;
    int n2 = (m/21)%21 - 10;
    int n3 = m%21 - 10;
    bool half = (n1 > 0) || (n1 == 0 && (n2 > 0 || (n2 == 0 && n3 > 0)));
    if (!half) continue;
    double d1 = n1, d2 = n2, d3 = n3;
    double kx = TWO_PI_D*(ivs[0]*d1 + ivs[1]*d2 + ivs[2]*d3);
    double ky = TWO_PI_D*(ivs[3]*d1 + ivs[4]*d2 + ivs[5]*d3);
    double kz = TWO_PI_D*(ivs[6]*d1 + ivs[7]*d2 + ivs[8]*d3);
    double k2 = kx*kx + ky*ky + kz*kz;
    if (k2 > 1e-10 && k2 < ksqmax) {
      double w = 2.0 * prefs * exp(-0.5*k2) / k2;
      int slot = atomicAdd(&cnt, 1);
      klist[b*KCAP + slot] = make_int4(n1, n2, n3, 0);
      kw[b*KCAP + slot] = w;
    }
  }
  __syncthreads();   // k-list complete before kcount
  // aug borders (plane0 real values; planes 1,2 zeroed by zero_planes)
  {
    const float* chi = nullptr; const int* znum = nullptr;
    classify2(c0, c1, c2, chi, znum);
    double* P0b = P0g + (size_t)b*NP1*WROW;
    for (int i = tid; i < NATOM; i += 256) {
      P0b[(size_t)NATOM*WROW + i] = 1.0;
      P0b[(size_t)i*WROW + NATOM] = 1.0;
      P0b[(size_t)i*WROW + 257]   = -(double)chi[b*NATOM + i];
    }
    if (tid == 0) {
      P0b[(size_t)NATOM*WROW + NATOM] = 0.0;
      P0b[(size_t)NATOM*WROW + 257]   = (double)syschg[b]*sqrt(90.0474);
      kcount[b] = cnt;
    }
  }
}

// ---------------- fp64 tile GEMM, ACCUMULATING into aug-geometry plane ----------
__device__ void gemm_tile(int b, int ti, int tj, int tid,
                          const double2* __restrict__ Tg,
                          const int4* __restrict__ klist,
                          const double* __restrict__ kw, int ks, int ke,
                          double* __restrict__ Ab, bool mirror, GemmSh& S)
{
  const int tx = tid & 15, ty = tid >> 4;
  const int ro = ty << 2, co = tx << 2;
  double acc[16];
#pragma unroll
  for (int i = 0; i < 16; i++) acc[i] = 0.0;

  for (int k0 = ks; k0 < ke; k0 += KC) {
    if (tid < KC) {
      int kk = k0 + tid;
      if (kk < ke) { S.kn[tid] = klist[b*KCAP + kk]; S.kw[tid] = kw[b*KCAP + kk]; }
      else         { S.kn[tid] = make_int4(0,0,0,0); S.kw[tid] = 0.0; }
    }
    __syncthreads();
#pragma unroll
    for (int p = 0; p < 8; p++) {
      int idx = p*256 + tid;
      int a    = idx & 63;
      int kk   = (idx >> 6) & (KC-1);
      int side = idx >> 10;
      int atom = ((side == 0) ? ti : tj) + a;
      int4 nn = S.kn[kk];
      double2 t1 = Tg[(size_t)((b*3+0)*21 + (nn.x+10))*256 + atom];
      double2 t2 = Tg[(size_t)((b*3+1)*21 + (nn.y+10))*256 + atom];
      double2 t3 = Tg[(size_t)((b*3+2)*21 + (nn.z+10))*256 + atom];
      double ex = t1.x*t2.x - t1.y*t2.y;
      double ey = t1.x*t2.y + t1.y*t2.x;
      double cx = ex*t3.x - ey*t3.y;
      double cy = ex*t3.y + ey*t3.x;
      if (side == 0) { double w = S.kw[kk]; S.cI[kk][a] = w*cx; S.sI[kk][a] = w*cy; }
      else           { S.cJ[kk][a] = cx; S.sJ[kk][a] = cy; }
    }
    __syncthreads();
#pragma unroll
    for (int kk = 0; kk < KC; kk++) {
      double ci[4], si[4], cj[4], sj[4];
#pragma unroll
      for (int r = 0; r < 2; r++) {
        double2 v0 = *(const double2*)&S.cI[kk][ro + 2*r];
        ci[2*r] = v0.x; ci[2*r+1] = v0.y;
        double2 v1 = *(const double2*)&S.sI[kk][ro + 2*r];
        si[2*r] = v1.x; si[2*r+1] = v1.y;
        double2 v2 = *(const double2*)&S.cJ[kk][co + 2*r];
        cj[2*r] = v2.x; cj[2*r+1] = v2.y;
        double2 v3 = *(const double2*)&S.sJ[kk][co + 2*r];
        sj[2*r] = v3.x; sj[2*r+1] = v3.y;
      }
#pragma unroll
      for (int r = 0; r < 4; r++)
#pragma unroll
        for (int c = 0; c < 4; c++)
          acc[r*4+c] += ci[r]*cj[c] + si[r]*sj[c];
    }
    __syncthreads();
  }
#pragma unroll
  for (int r = 0; r < 4; r++) {
#pragma unroll
    for (int c = 0; c < 4; c++) {
      int gr = ti + ro + r, gc = tj + co + c;
      double v = acc[r*4+c];
      atomAddD(&Ab[(size_t)gr*WROW + gc], v);
      if (mirror && ti != tj) atomAddD(&Ab[(size_t)gc*WROW + gr], v);
    }
  }
}

__device__ __forceinline__ double* plane_sel(double* P0, double* P1, double* P2, int s) {
  return (s == 0) ? P0 : ((s == 1) ? P1 : P2);
}

// ---------------- K2 (grid 160*nplanes): tiles x batches x 2*nplanes k-segments ----
// r9-proven 6-way k-split (r10 lesson: 12-way doubles fp64-atomic traffic and
// REGRESSES ~50us; 6-way is the sweet spot).
__global__ __launch_bounds__(256) void build_A_gemm(
    const double2* __restrict__ Tg, const int4* __restrict__ klist,
    const double* __restrict__ kw, const int* __restrict__ kcount,
    double* __restrict__ P0g, double* __restrict__ P1g, double* __restrict__ P2g,
    int nplanes)
{
  __shared__ GemmSh S;
  const int nseg = 2*nplanes;
  const int u = blockIdx.x;
  const int seg = u / 80;
  const int r = u - seg*80;
  const int b = r / 10;
  const int t = r - b*10;
  const int s = (seg < nplanes) ? seg : (seg - nplanes);
  const int cnt = kcount[b];
  const int ks = (int)((long long)cnt * seg / nseg);
  const int ke = (int)((long long)cnt * (seg+1) / nseg);
  double* Ab = plane_sel(P0g, P1g, P2g, s) + (size_t)b*NP1*WROW;
  gemm_tile(b, TI10[t]*64, TJ10[t]*64, threadIdx.x, Tg, klist, kw, ks, ke, Ab, true, S);
}

// ---------------- K4a (grid 8, block 768): no-pivot blocked LU factor, NB=16 ----
// r7 phase structure, widened 512 -> 768 threads (12 waves): +50% TLP for the
// latency-bound phases. launch_bounds(768,2) keeps the 256-VGPR cap that gave the
// clean 92-VGPR allocation at 512 (the 1024-thread config triggers the 64-VGPR
// heuristic and spills -- rounds 0/4).
__global__ __launch_bounds__(BDF, 2) void solve_factor(
    double* __restrict__ P0g, const double* __restrict__ P1g, const double* __restrict__ P2g,
    int nplanes,
    const void* __restrict__ c0, const void* __restrict__ c1, const void* __restrict__ c2,
    const float* __restrict__ Jraw)
{
  const int b = blockIdx.x;
  const int tid = threadIdx.x;
  double* Pb = P0g + (size_t)b*NP1*WROW;
  const double* Qb = P1g + (size_t)b*NP1*WROW;
  const double* Rb = P2g + (size_t)b*NP1*WROW;
  const bool two   = (nplanes > 1);
  const bool three = (nplanes > 2);

  __shared__ __align__(16) double pan[NP1+4][NB+2];  // +4 rows: OOB-read pad for 2-row tiles
  __shared__ double dnv[NB];
  __shared__ __align__(16) double Ub[NB][UBW];

  const float* chi = nullptr; const int* znum = nullptr;
  classify2(c0, c1, c2, chi, znum);
  const float J0 = Jraw[0], J1 = Jraw[1], J2 = Jraw[2], J3 = Jraw[3];

  for (int p0 = 0; p0 < NP1; p0 += NB) {
    const int pw  = (NB < NP1 - p0) ? NB : (NP1 - p0);   // 16 x16 panels, then 1
    const int nr  = NP1 - p0;
    const int nrt = nr - pw;
    const int tc0 = p0 + pw;
    const int tc  = WROW - tc0;
    const bool first = (p0 == 0);
    // ---- 1. panel load (first panel: fused plane-sum + J-diag) ----
    for (int idx = tid; idx < nr*pw; idx += BDF) {
      int r, c;
      if (pw == NB) { r = idx >> 4; c = idx & 15; } else { r = idx; c = 0; }
      double v;
      if (first) {
        size_t a = (size_t)r*WROW + c;
        v = Pb[a];
        if (two)   v += Qb[a];
        if (three) v += Rb[a];
        if (r == c) {
          int z = znum[b*NATOM + r];
          float Jr = (z == 1) ? J0 : (z == 6) ? J1 : (z == 7) ? J2 : J3;
          v += (double)Jr*(double)Jr - DIAG_SUB;
        }
      } else {
        v = Pb[(size_t)(p0+r)*WROW + p0 + c];
      }
      pan[r][c] = v;
    }
    __syncthreads();
    // ---- 2. diag 16x16 factor: 16 lanes, rows in registers, shfl-on-demand ----
    if (pw == NB) {
      if (tid < NB) {
        double v[NB];
#pragma unroll
        for (int c = 0; c < NB; c++) v[c] = pan[tid][c];
#pragma unroll
        for (int c = 0; c < NB; c++) {
          double piv = __shfl(v[c], c);
          double dinv = 1.0 / piv;
          if (tid == c) dnv[c] = dinv;
          double f = v[c] * dinv;          // only meaningful for tid > c
#pragma unroll
          for (int cc = 0; cc < NB; cc++) {
            if (cc > c) {
              double ucc = __shfl(v[cc], c);
              if (tid > c) v[cc] -= f * ucc;
            }
          }
          if (tid > c) v[c] = f;
        }
#pragma unroll
        for (int c = 0; c < NB; c++) pan[tid][c] = v[c];
      }
    }
    __syncthreads();
    // ---- 3+4. L21 row-TRSM (tid<nrt) || U12 col-TRSM (tid 256..256+tc) || U11
    //           write-back (all other threads incl. 512..767). Reads-only pan;
    //           writes disjoint. nrt<=241<256, tc<=242 -> 256+tc<=498<512. ----
    if (pw == NB) {
      if (tid < nrt) {
        const int r = NB + tid;
        double w[NB];
#pragma unroll
        for (int c = 0; c < NB; c++) w[c] = pan[r][c];
#pragma unroll
        for (int c = 0; c < NB; c++) {
          double s = w[c];
#pragma unroll
          for (int c2 = 0; c2 < NB; c2++) if (c2 < c) s -= w[c2] * pan[c2][c];
          w[c] = s * dnv[c];
        }
#pragma unroll
        for (int c = 0; c < NB; c++) pan[r][c] = w[c];
      } else if (tid >= 256 && tid < 256 + tc) {
        const int j = tc0 + (tid - 256);
        double v[NB];
#pragma unroll
        for (int c = 0; c < NB; c++) {
          size_t a = (size_t)(p0+c)*WROW + j;
          double t = Pb[a];
          if (first) {
            if (two)   t += Qb[a];
            if (three) t += Rb[a];
          }
          v[c] = t;
        }
#pragma unroll
        for (int c = 0; c < NB; c++)
#pragma unroll
          for (int r2 = 0; r2 < NB; r2++) if (r2 > c) v[r2] -= pan[r2][c]*v[c];
#pragma unroll
        for (int c = 0; c < NB; c++) {
          Pb[(size_t)(p0+c)*WROW + j] = v[c];
          Ub[c][tid - 256] = v[c];
        }
      } else {
        // U11/L11 write-back for the backsolve. Idle threads: [nrt,256) and
        // [256+tc, BDF); hid is contiguous over both ranges.
        const int nh = (256 - nrt) + (BDF - 256 - tc);
        int hid = (tid < 256) ? (tid - nrt) : ((256 - nrt) + (tid - 256 - tc));
        for (int idx = hid; idx < NB*NB; idx += nh) {
          int r2 = idx >> 4, c2 = idx & 15;
          Pb[(size_t)(p0+r2)*WROW + p0 + c2] = pan[r2][c2];
        }
      }
    } else {
      if (tid == 0) Pb[(size_t)p0*WROW + p0] = pan[0][0];
    }
    __syncthreads();
    // ---- 5. trailing rank-16 update: 128 col-pair lanes x 6 row-groups x 2 rows.
    //         va/vb REGISTER-resident; next row-pair prefetched into regs before
    //         the FMA loop. ----
    if (pw == NB) {
      const int jp   = tid & 127;
      const int rowg = tid >> 7;        // 0..5, wave-uniform
      const int j0 = 2*jp;
      if (j0 < tc && nrt > 0) {
        double va[NB], vb[NB];
#pragma unroll
        for (int c = 0; c < NB; c++) {
          double2 u = *(const double2*)&Ub[c][j0];
          va[c] = u.x; vb[c] = u.y;
        }
        auto loadrow = [&](int rr, double2& x0, double2& x1) {
          x0 = make_double2(0.0, 0.0); x1 = x0;
          if (rr < nrt) {
            const int row0 = tc0 + rr;
            const size_t ad = (size_t)row0*WROW + tc0 + j0;
            x0 = *(const double2*)&Pb[ad];
            if (rr + 1 < nrt) x1 = *(const double2*)&Pb[ad + WROW];
            if (first) {
              if (two) {
                double2 q0 = *(const double2*)&Qb[ad]; x0.x += q0.x; x0.y += q0.y;
                if (rr + 1 < nrt) { double2 q1 = *(const double2*)&Qb[ad + WROW]; x1.x += q1.x; x1.y += q1.y; }
              }
              if (three) {
                double2 r0v = *(const double2*)&Rb[ad]; x0.x += r0v.x; x0.y += r0v.y;
                if (rr + 1 < nrt) { double2 r1v = *(const double2*)&Rb[ad + WROW]; x1.x += r1v.x; x1.y += r1v.y; }
              }
              if (rr == j0) {             // rr even == j0 even: diag hits are
                if (row0 < NATOM) {       // (rr,j0)->x0.x and (rr+1,j1)->x1.y
                  int z = znum[b*NATOM + row0];
                  float Jr = (z == 1) ? J0 : (z == 6) ? J1 : (z == 7) ? J2 : J3;
                  x0.x += (double)Jr*(double)Jr - DIAG_SUB;
                }
                if (rr + 1 < nrt && row0 + 1 < NATOM) {
                  int z = znum[b*NATOM + row0 + 1];
                  float Jr = (z == 1) ? J0 : (z == 6) ? J1 : (z == 7) ? J2 : J3;
                  x1.y += (double)Jr*(double)Jr - DIAG_SUB;
                }
              }
            }
          }
        };
        int rr = 2*rowg;
        double2 a0, a1;
        loadrow(rr, a0, a1);
        while (rr < nrt) {
          const int rn = rr + 12;        // 6 row-groups x 2 rows
          double2 n0, n1;
          loadrow(rn, n0, n1);             // prefetch next iteration's rows
          const double* pr0 = pan[NB + rr];
          const double* pr1 = pan[NB + rr + 1];   // padded row when rr+1==nrt
#pragma unroll
          for (int m = 0; m < NB/2; m++) {
            double2 l0 = *(const double2*)&pr0[2*m];
            double2 l1 = *(const double2*)&pr1[2*m];
            a0.x -= l0.x*va[2*m] + l0.y*va[2*m+1];
            a0.y -= l0.x*vb[2*m] + l0.y*vb[2*m+1];
            a1.x -= l1.x*va[2*m] + l1.y*va[2*m+1];
            a1.y -= l1.x*vb[2*m] + l1.y*vb[2*m+1];
          }
          const size_t ad = (size_t)(tc0+rr)*WROW + tc0 + j0;
          *(double2*)&Pb[ad] = a0;
          if (rr + 1 < nrt) *(double2*)&Pb[ad + WROW] = a1;
          a0 = n0; a1 = n1;
          rr = rn;
        }
      }
    }
    __syncthreads();
  }
}

// ---------------- K4b (grid 8, block 256): backsolve + outputs ----------------
__global__ __launch_bounds__(BDB) void solve_back(
    double* __restrict__ P0g,
    const void* __restrict__ c0, const void* __restrict__ c1, const void* __restrict__ c2,
    const float* __restrict__ Jraw, const float* __restrict__ syschg,
    float* __restrict__ out)
{
  const int b = blockIdx.x;
  const int tid = threadIdx.x;
  double* Pb = P0g + (size_t)b*NP1*WROW;

  __shared__ double panb[NB][NB+1];
  __shared__ double xs[NP1];
  __shared__ double red[BDB];

  const float* chi = nullptr; const int* znum = nullptr;
  classify2(c0, c1, c2, chi, znum);
  const double rhsN = (double)syschg[b] * sqrt(90.0474);
  const float J0 = Jraw[0], J1 = Jraw[1], J2 = Jraw[2], J3 = Jraw[3];

  for (int r = tid; r < NP1; r += BDB) xs[r] = Pb[(size_t)r*WROW + 257];
  __syncthreads();
  for (int pb0 = 256; pb0 >= 0; pb0 -= NB) {
    const int w = (pb0 == 256) ? 1 : NB;
    if (w == NB) {
      {
        const int i = tid >> 4, c = tid & 15;
        panb[i][c] = Pb[(size_t)(pb0+i)*WROW + pb0 + c];
      }
      __syncthreads();
      if (tid < NB) {
        double u[NB];
#pragma unroll
        for (int c = 0; c < NB; c++) u[c] = panb[tid][c];
        double y  = xs[pb0 + tid];
        double di = 1.0 / panb[tid][tid];   // direct LDS read, no dynamic reg index
        double xr = 0.0;
#pragma unroll
        for (int i = NB-1; i >= 0; i--) {
          double xi = y * di;            // only lane i's value is consumed
          xi = __shfl(xi, i);
          if (tid == i) xr = xi;
          if (tid < i)  y -= u[i] * xi;
        }
        xs[pb0 + tid] = xr;
      }
    } else {
      if (tid == 0) xs[256] = xs[256] / Pb[(size_t)256*WROW + 256];
    }
    __syncthreads();
    if (tid < pb0) {
      const double* rowp = &Pb[(size_t)tid*WROW + pb0];
      double s = 0.0;
      for (int c = 0; c < w; c++) s += rowp[c]*xs[pb0+c];
      xs[tid] -= s;
    }
    __syncthreads();
  }

  // ---- outputs: q + residual-identity energy ----
  out[b*NATOM + tid] = (float)xs[tid];
  const double lam = xs[NATOM];
  double q  = xs[tid];
  double ch = (double)chi[b*NATOM + tid];
  int z = znum[b*NATOM + tid];
  float Jr = (z == 1) ? J0 : (z == 6) ? J1 : (z == 7) ? J2 : J3;
  red[tid] = q*ch + (double)Jr*(double)Jr*q*q;
  __syncthreads();
  for (int st = BDB/2; st > 0; st >>= 1) {
    if (tid < st) red[tid] += red[tid + st];
    __syncthreads();
  }
  if (tid == 0)
    out[NBATCH*NATOM + b] = (float)(-0.5*(red[0] + lam*rhsN));
}

// ---------------- host launch ----------------
extern "C" void kernel_launch(void* const* d_in, const int* in_sizes, int n_in,
                              void* d_out, int out_size, void* d_ws, size_t ws_size,
                              hipStream_t stream)
{
  int iPos=-1, iCell=-1, iJ=-1, iQ=-1, cand[3]={-1,-1,-1}, nc=0;
  for (int i = 0; i < n_in; i++) {
    int s = in_sizes[i];
    if      (s == 6144) iPos  = i;
    else if (s == 72)   iCell = i;
    else if (s == 4)    iJ    = i;
    else if (s == 8)    iQ    = i;
    else if (s == 2048 && nc < 3) cand[nc++] = i;
  }
  if (!(iPos>=0 && iCell>=0 && iJ>=0 && iQ>=0 && nc>=2)) {
    iPos=iCell=iJ=iQ=-1; nc=0; cand[0]=cand[1]=cand[2]=-1;
    for (int i = 0; i < n_in; i++) {
      int s = in_sizes[i];
      if      (s == 24576) iPos  = i;
      else if (s == 288)   iCell = i;
      else if (s == 16)    iJ    = i;
      else if (s == 32)    iQ    = i;
      else if (s == 8192 && nc < 3) cand[nc++] = i;
    }
  }
  if (!(iPos>=0 && iCell>=0 && iJ>=0 && iQ>=0 && nc>=2)) {
    iPos=0; iCell=1; iJ=3; iQ=4; cand[0]=2; cand[1]=5; cand[2]=6; nc=3;
  }
  if (nc == 2) cand[2] = cand[1];

  const float* pos  = (const float*)d_in[iPos];
  const float* cell = (const float*)d_in[iCell];
  const float* Jraw = (const float*)d_in[iJ];
  const float* sysq = (const float*)d_in[iQ];
  const void*  c0   = d_in[cand[0]];
  const void*  c1   = d_in[cand[1]];
  const void*  c2   = d_in[cand[2]];
  float* out = (float*)d_out;

  // ws: [plane0][plane1][plane2][Tg][klist][kw][kcount]
  const size_t planeB = (size_t)NBATCH*NP1*WROW*sizeof(double);  // 4,243,584
  const size_t tgB = 2064384, klB = 327680, kwB = 163840;
  const size_t trigAll = tgB + klB + kwB + 64;
  int nplanes = (ws_size >= 3*planeB + trigAll) ? 3 :
                ((ws_size >= 2*planeB + trigAll) ? 2 : 1);

  char* ws = (char*)d_ws;
  double*  P0g = (double*)ws;
  double*  P1g = (nplanes > 1) ? (double*)(ws + planeB)   : P0g;
  double*  P2g = (nplanes > 2) ? (double*)(ws + 2*planeB) : P1g;
  char* trigBase = ws + (size_t)nplanes*planeB;
  double2* Tg     = (double2*)trigBase;
  int4*    klist  = (int4*)  (trigBase + tgB);
  double*  kwa    = (double*)(trigBase + tgB + klB);
  int*     kcount = (int*)   (trigBase + tgB + klB + kwB);

  hipLaunchKernelGGL(zero_planes,  dim3(512),           dim3(256), 0, stream,
                     P0g, nplanes);
  hipLaunchKernelGGL(prep,         dim3(NBATCH),        dim3(256), 0, stream,
                     pos, cell, Tg, klist, kwa, kcount, c0, c1, c2, sysq,
                     P0g, nplanes);
  hipLaunchKernelGGL(build_A_gemm, dim3(160*nplanes),   dim3(256), 0, stream,
                     Tg, klist, kwa, kcount, P0g, P1g, P2g, nplanes);
  hipLaunchKernelGGL(solve_factor, dim3(NBATCH),        dim3(BDF), 0, stream,
                     P0g, P1g, P2g, nplanes, c0, c1, c2, Jraw);
  hipLaunchKernelGGL(solve_back,   dim3(NBATCH),        dim3(BDB), 0, stream,
                     P0g, c0, c1, c2, Jraw, sysq, out);
}

// Round 13
// 591.064 us; speedup vs baseline: 1.1704x; 1.0585x over previous
//
#include <hip/hip_runtime.h>
#include <math.h>

#define NBATCH 8
#define NATOM  256
#define NP1    257
#define WROW   258
#define TOTALK 9261
#define KCAP   2560
#define KC     16
#define NB     16
#define UBW    124
#define BDF    768
#define BDB    256
#define FLAGOFF 2528          /* int4 slot where per-batch flags live in klist tail */
#define SLOTMAX 2500          /* prep never writes k-entries at/above this slot */

#define TWO_PI_D 6.283185307179586
#define DIAG_SUB 0.7978845608028654   /* 2/sqrt(2*pi) */

__device__ __constant__ int TI10[10] = {0,0,0,0,1,1,1,2,2,3};
__device__ __constant__ int TJ10[10] = {0,1,2,3,1,2,3,2,3,3};

struct GemmSh {
  int4   kn[KC];
  double kw[KC];
  double cI[KC][64], sI[KC][64];
  double cJ[KC][64], sJ[KC][64];
};

// HW fp64 atomic add (gfx90a+/gfx950); CAS fallback if builtin missing.
__device__ __forceinline__ void atomAddD(double* p, double v) {
#if defined(__has_builtin)
#if __has_builtin(__builtin_amdgcn_global_atomic_fadd_f64)
  __builtin_amdgcn_global_atomic_fadd_f64(p, v);
  return;
#endif
#endif
  unsigned long long* u = (unsigned long long*)p;
  unsigned long long old = *u, assumed;
  do {
    assumed = old;
    old = atomicCAS(u, assumed,
                    (unsigned long long)__double_as_longlong(
                        v + __longlong_as_double((long long)assumed)));
  } while (old != assumed);
}

__device__ __forceinline__ void classify2(const void* c0, const void* c1, const void* c2,
                                          const float*& chi, const int*& znum)
{
  const void* cands[3] = {c0, c1, c2};
  int got = 0;
  for (int i = 0; i < 3; i++) {
    unsigned uu = ((const unsigned*)cands[i])[0];
    if (uu == 0u) continue;                                      // batch
    else if (uu < 16u) { znum = (const int*)cands[i]; got |= 1; }// z in {1,6,7,8}
    else               { chi  = (const float*)cands[i]; got |= 2; }
  }
  if (got != 3) { chi = (const float*)c0; znum = (const int*)c1; }
}

// ---------------- K0 (grid 512): zero A-planes + factor sync flags ----------------
__global__ __launch_bounds__(256) void zero_planes(
    double* __restrict__ P0g, int4* __restrict__ klist, int nplanes)
{
  if (blockIdx.x == 0 && threadIdx.x < 256) {
    const int b = threadIdx.x >> 5, s = threadIdx.x & 31;
    klist[(size_t)b*KCAP + FLAGOFF + s] = make_int4(0, 0, 0, 0);
  }
  const size_t npair = (size_t)nplanes * NBATCH * ((NP1*WROW) >> 1);
  double2* Z = (double2*)P0g;   // planes are contiguous: [P0][P1][P2]
  const double2 z = make_double2(0.0, 0.0);
  for (size_t i = (size_t)blockIdx.x*256 + threadIdx.x; i < npair;
       i += (size_t)gridDim.x*256)
    Z[i] = z;
}

// ---------------- K1 (grid 8): trig tables + k-list + aug borders ----------------
__global__ __launch_bounds__(256) void prep(
    const float* __restrict__ pos, const float* __restrict__ cell,
    double2* __restrict__ Tg, int4* __restrict__ klist,
    double* __restrict__ kw, int* __restrict__ kcount,
    const void* __restrict__ c0, const void* __restrict__ c1, const void* __restrict__ c2,
    const float* __restrict__ syschg,
    double* __restrict__ P0g, int nplanes)
{
  const int b = blockIdx.x;
  const int tid = threadIdx.x;
  __shared__ double ivs[9];
  __shared__ double prefs;
  __shared__ int cnt;
  if (tid == 0) {
    double c[9];
#pragma unroll
    for (int i = 0; i < 9; i++) c[i] = (double)cell[b*9+i];
    double det = c[0]*(c[4]*c[8]-c[5]*c[7]) - c[1]*(c[3]*c[8]-c[5]*c[6])
               + c[2]*(c[3]*c[7]-c[4]*c[6]);
    double idet = 1.0/det;
    ivs[0]=(c[4]*c[8]-c[5]*c[7])*idet; ivs[1]=(c[2]*c[7]-c[1]*c[8])*idet; ivs[2]=(c[1]*c[5]-c[2]*c[4])*idet;
    ivs[3]=(c[5]*c[6]-c[3]*c[8])*idet; ivs[4]=(c[0]*c[8]-c[2]*c[6])*idet; ivs[5]=(c[2]*c[3]-c[0]*c[5])*idet;
    ivs[6]=(c[3]*c[7]-c[4]*c[6])*idet; ivs[7]=(c[1]*c[6]-c[0]*c[7])*idet; ivs[8]=(c[0]*c[4]-c[1]*c[3])*idet;
    prefs = 2.0*TWO_PI_D/fabs(det);
    cnt = 0;
  }
  __syncthreads();
  {
    const int a = tid;
    double x = (double)pos[((size_t)b*NATOM+a)*3+0];
    double y = (double)pos[((size_t)b*NATOM+a)*3+1];
    double z = (double)pos[((size_t)b*NATOM+a)*3+2];
    double u[3];
    u[0] = TWO_PI_D*(ivs[0]*x + ivs[3]*y + ivs[6]*z);
    u[1] = TWO_PI_D*(ivs[1]*x + ivs[4]*y + ivs[7]*z);
    u[2] = TWO_PI_D*(ivs[2]*x + ivs[5]*y + ivs[8]*z);
#pragma unroll
    for (int d = 0; d < 3; d++) {
      double2* T = Tg + (size_t)((b*3 + d)*21)*256;
      double c1 = cos(u[d]);
      double s1 = sin(u[d]);
      T[10*256 + a] = make_double2(1.0, 0.0);
      T[11*256 + a] = make_double2(c1,  s1);
      T[ 9*256 + a] = make_double2(c1, -s1);
      double cp = c1, sp = s1;
      for (int n = 2; n <= 10; n++) {
        double cn = cp*c1 - sp*s1;
        double sn = sp*c1 + cp*s1;
        cp = cn; sp = sn;
        T[(10+n)*256 + a] = make_double2(cp,  sp);
        T[(10-n)*256 + a] = make_double2(cp, -sp);
      }
    }
  }
  const double ksqmax = (TWO_PI_D/1.5)*(TWO_PI_D/1.5);
  for (int m = tid; m < TOTALK; m += 256) {
    int n1 = m/441 - 10;
    int n2 = (m/21)%21 - 10;
    int n3 = m%21 - 10;
    bool half = (n1 > 0) || (n1 == 0 && (n2 > 0 || (n2 == 0 && n3 > 0)));
    if (!half) continue;
    double d1 = n1, d2 = n2, d3 = n3;
    double kx = TWO_PI_D*(ivs[0]*d1 + ivs[1]*d2 + ivs[2]*d3);
    double ky = TWO_PI_D*(ivs[3]*d1 + ivs[4]*d2 + ivs[5]*d3);
    double kz = TWO_PI_D*(ivs[6]*d1 + ivs[7]*d2 + ivs[8]*d3);
    double k2 = kx*kx + ky*ky + kz*kz;
    if (k2 > 1e-10 && k2 < ksqmax) {
      double w = 2.0 * prefs * exp(-0.5*k2) / k2;
      int slot = atomicAdd(&cnt, 1);
      if (slot < SLOTMAX) {               // protect flag region (cnt ~2100 in practice)
        klist[b*KCAP + slot] = make_int4(n1, n2, n3, 0);
        kw[b*KCAP + slot] = w;
      }
    }
  }
  __syncthreads();   // k-list complete before kcount
  // aug borders (plane0 real values; planes 1,2 zeroed by zero_planes)
  {
    const float* chi = nullptr; const int* znum = nullptr;
    classify2(c0, c1, c2, chi, znum);
    double* P0b = P0g + (size_t)b*NP1*WROW;
    for (int i = tid; i < NATOM; i += 256) {
      P0b[(size_t)NATOM*WROW + i] = 1.0;
      P0b[(size_t)i*WROW + NATOM] = 1.0;
      P0b[(size_t)i*WROW + 257]   = -(double)chi[b*NATOM + i];
    }
    if (tid == 0) {
      P0b[(size_t)NATOM*WROW + NATOM] = 0.0;
      P0b[(size_t)NATOM*WROW + 257]   = (double)syschg[b]*sqrt(90.0474);
      kcount[b] = (cnt < SLOTMAX) ? cnt : SLOTMAX;
    }
  }
}

// ---------------- fp64 tile GEMM, ACCUMULATING into aug-geometry plane ----------
__device__ void gemm_tile(int b, int ti, int tj, int tid,
                          const double2* __restrict__ Tg,
                          const int4* __restrict__ klist,
                          const double* __restrict__ kw, int ks, int ke,
                          double* __restrict__ Ab, bool mirror, GemmSh& S)
{
  const int tx = tid & 15, ty = tid >> 4;
  const int ro = ty << 2, co = tx << 2;
  double acc[16];
#pragma unroll
  for (int i = 0; i < 16; i++) acc[i] = 0.0;

  for (int k0 = ks; k0 < ke; k0 += KC) {
    if (tid < KC) {
      int kk = k0 + tid;
      if (kk < ke) { S.kn[tid] = klist[b*KCAP + kk]; S.kw[tid] = kw[b*KCAP + kk]; }
      else         { S.kn[tid] = make_int4(0,0,0,0); S.kw[tid] = 0.0; }
    }
    __syncthreads();
#pragma unroll
    for (int p = 0; p < 8; p++) {
      int idx = p*256 + tid;
      int a    = idx & 63;
      int kk   = (idx >> 6) & (KC-1);
      int side = idx >> 10;
      int atom = ((side == 0) ? ti : tj) + a;
      int4 nn = S.kn[kk];
      double2 t1 = Tg[(size_t)((b*3+0)*21 + (nn.x+10))*256 + atom];
      double2 t2 = Tg[(size_t)((b*3+1)*21 + (nn.y+10))*256 + atom];
      double2 t3 = Tg[(size_t)((b*3+2)*21 + (nn.z+10))*256 + atom];
      double ex = t1.x*t2.x - t1.y*t2.y;
      double ey = t1.x*t2.y + t1.y*t2.x;
      double cx = ex*t3.x - ey*t3.y;
      double cy = ex*t3.y + ey*t3.x;
      if (side == 0) { double w = S.kw[kk]; S.cI[kk][a] = w*cx; S.sI[kk][a] = w*cy; }
      else           { S.cJ[kk][a] = cx; S.sJ[kk][a] = cy; }
    }
    __syncthreads();
#pragma unroll
    for (int kk = 0; kk < KC; kk++) {
      double ci[4], si[4], cj[4], sj[4];
#pragma unroll
      for (int r = 0; r < 2; r++) {
        double2 v0 = *(const double2*)&S.cI[kk][ro + 2*r];
        ci[2*r] = v0.x; ci[2*r+1] = v0.y;
        double2 v1 = *(const double2*)&S.sI[kk][ro + 2*r];
        si[2*r] = v1.x; si[2*r+1] = v1.y;
        double2 v2 = *(const double2*)&S.cJ[kk][co + 2*r];
        cj[2*r] = v2.x; cj[2*r+1] = v2.y;
        double2 v3 = *(const double2*)&S.sJ[kk][co + 2*r];
        sj[2*r] = v3.x; sj[2*r+1] = v3.y;
      }
#pragma unroll
      for (int r = 0; r < 4; r++)
#pragma unroll
        for (int c = 0; c < 4; c++)
          acc[r*4+c] += ci[r]*cj[c] + si[r]*sj[c];
    }
    __syncthreads();
  }
#pragma unroll
  for (int r = 0; r < 4; r++) {
#pragma unroll
    for (int c = 0; c < 4; c++) {
      int gr = ti + ro + r, gc = tj + co + c;
      double v = acc[r*4+c];
      atomAddD(&Ab[(size_t)gr*WROW + gc], v);
      if (mirror && ti != tj) atomAddD(&Ab[(size_t)gc*WROW + gr], v);
    }
  }
}

__device__ __forceinline__ double* plane_sel(double* P0, double* P1, double* P2, int s) {
  return (s == 0) ? P0 : ((s == 1) ? P1 : P2);
}

// ---------------- K2 (grid 160*nplanes): tiles x batches x 2*nplanes k-segments ----
__global__ __launch_bounds__(256) void build_A_gemm(
    const double2* __restrict__ Tg, const int4* __restrict__ klist,
    const double* __restrict__ kw, const int* __restrict__ kcount,
    double* __restrict__ P0g, double* __restrict__ P1g, double* __restrict__ P2g,
    int nplanes)
{
  __shared__ GemmSh S;
  const int nseg = 2*nplanes;
  const int u = blockIdx.x;
  const int seg = u / 80;
  const int r = u - seg*80;
  const int b = r / 10;
  const int t = r - b*10;
  const int s = (seg < nplanes) ? seg : (seg - nplanes);
  const int cnt = kcount[b];
  const int ks = (int)((long long)cnt * seg / nseg);
  const int ke = (int)((long long)cnt * (seg+1) / nseg);
  double* Ab = plane_sel(P0g, P1g, P2g, s) + (size_t)b*NP1*WROW;
  gemm_tile(b, TI10[t]*64, TJ10[t]*64, threadIdx.x, Tg, klist, kw, ks, ke, Ab, true, S);
}

// ---------------- K4a (grid 16, block 768): column-split no-pivot LU factor -----
// 2 CUs per batch, h=0 left / h=1 right trailing columns per panel. r12 LESSON:
// the split point moves right ~8 cols per panel, so columns TRANSITION h1->h0
// between panels; the one-directional flag scheme raced on that band (absmax 1e10).
// FIX: full two-block barrier per panel -- both blocks wait for BOTH prev-panel
// flags before starting. Within a panel writes are disjoint (own columns; U11 to
// scratch so raw panel data in Pb is never overwritten); across panels the barrier
// orders everything. 16 L2-atomic round-trips ~ a few us total.
__global__ __launch_bounds__(BDF, 2) void solve_factor(
    double* __restrict__ P0g, const double* __restrict__ P1g, const double* __restrict__ P2g,
    int nplanes,
    const void* __restrict__ c0, const void* __restrict__ c1, const void* __restrict__ c2,
    const float* __restrict__ Jraw,
    int4* __restrict__ klist, double* __restrict__ U11g)
{
  const int b = blockIdx.x >> 1;
  const int h = blockIdx.x & 1;
  const int tid = threadIdx.x;
  double* Pb = P0g + (size_t)b*NP1*WROW;
  const double* Qb = P1g + (size_t)b*NP1*WROW;
  const double* Rb = P2g + (size_t)b*NP1*WROW;
  const bool two   = (nplanes > 1);
  const bool three = (nplanes > 2);
  int* FA = (int*)(klist + (size_t)b*KCAP + FLAGOFF);   // FA[p]: h0 done panel p
  int* FB = FA + 32;                                     // FB[p]: h1 done panel p
  double* U11b = U11g + (size_t)b*17*256;

  __shared__ __align__(16) double pan[NP1+4][NB+2];
  __shared__ double dnv[NB];
  __shared__ __align__(16) double Ub[NB][UBW];

  const float* chi = nullptr; const int* znum = nullptr;
  classify2(c0, c1, c2, chi, znum);
  const float J0 = Jraw[0], J1 = Jraw[1], J2 = Jraw[2], J3 = Jraw[3];

  int p = 0;
  for (int p0 = 0; p0 < NP1; p0 += NB, p++) {
    const int pw  = (NB < NP1 - p0) ? NB : (NP1 - p0);
    const int nr  = NP1 - p0;
    const int nrt = nr - pw;
    const int tc0 = p0 + pw;
    const int tc  = WROW - tc0;                         // even
    const bool first = (p0 == 0);
    // column split (even sizes): left gets ceil-half rounded to even
    int leftCols = (tc >= 4) ? (((tc >> 1) + 1) & ~1) : tc;
    const int clo = (h == 0) ? tc0 : tc0 + leftCols;
    const int chiC = (h == 0) ? tc0 + leftCols : tc0 + tc;
    const int ownCols = chiC - clo;
    // ---- full inter-block barrier: both prev-panel flags must be up ----
    if (p > 0) {
      if (tid == 0) {
        while (atomicAdd(&FA[p-1], 0) == 0) __builtin_amdgcn_s_sleep(2);
        while (atomicAdd(&FB[p-1], 0) == 0) __builtin_amdgcn_s_sleep(2);
        __threadfence();
      }
      __syncthreads();
    }
    // ---- 1. panel load (both blocks; first panel fuses plane-sum + J-diag) ----
    for (int idx = tid; idx < nr*pw; idx += BDF) {
      int r, c;
      if (pw == NB) { r = idx >> 4; c = idx & 15; } else { r = idx; c = 0; }
      double v;
      if (first) {
        size_t a = (size_t)r*WROW + c;
        v = Pb[a];
        if (two)   v += Qb[a];
        if (three) v += Rb[a];
        if (r == c) {
          int z = znum[b*NATOM + r];
          float Jr = (z == 1) ? J0 : (z == 6) ? J1 : (z == 7) ? J2 : J3;
          v += (double)Jr*(double)Jr - DIAG_SUB;
        }
      } else {
        v = Pb[(size_t)(p0+r)*WROW + p0 + c];
      }
      pan[r][c] = v;
    }
    __syncthreads();
    // ---- 2. diag 16x16 factor (both blocks, redundant on h1) ----
    if (pw == NB) {
      if (tid < NB) {
        double v[NB];
#pragma unroll
        for (int c = 0; c < NB; c++) v[c] = pan[tid][c];
#pragma unroll
        for (int c = 0; c < NB; c++) {
          double piv = __shfl(v[c], c);
          double dinv = 1.0 / piv;
          if (tid == c) dnv[c] = dinv;
          double f = v[c] * dinv;
#pragma unroll
          for (int cc = 0; cc < NB; cc++) {
            if (cc > c) {
              double ucc = __shfl(v[cc], c);
              if (tid > c) v[cc] -= f * ucc;
            }
          }
          if (tid > c) v[c] = f;
        }
#pragma unroll
        for (int c = 0; c < NB; c++) pan[tid][c] = v[c];
      }
    }
    __syncthreads();
    // ---- 3. L21 TRSM (both) || U12 TRSM own cols || U11 -> scratch (h0) ----
    if (pw == NB) {
      if (tid < nrt) {
        const int r = NB + tid;
        double w[NB];
#pragma unroll
        for (int c = 0; c < NB; c++) w[c] = pan[r][c];
#pragma unroll
        for (int c = 0; c < NB; c++) {
          double s = w[c];
#pragma unroll
          for (int c2 = 0; c2 < NB; c2++) if (c2 < c) s -= w[c2] * pan[c2][c];
          w[c] = s * dnv[c];
        }
#pragma unroll
        for (int c = 0; c < NB; c++) pan[r][c] = w[c];
      } else if (tid >= 256 && tid < 256 + ownCols) {
        const int j = clo + (tid - 256);
        double v[NB];
#pragma unroll
        for (int c = 0; c < NB; c++) {
          size_t a = (size_t)(p0+c)*WROW + j;
          double t = Pb[a];
          if (first) {
            if (two)   t += Qb[a];
            if (three) t += Rb[a];
          }
          v[c] = t;
        }
#pragma unroll
        for (int c = 0; c < NB; c++)
#pragma unroll
          for (int r2 = 0; r2 < NB; r2++) if (r2 > c) v[r2] -= pan[r2][c]*v[c];
#pragma unroll
        for (int c = 0; c < NB; c++) {
          Pb[(size_t)(p0+c)*WROW + j] = v[c];
          Ub[c][tid - 256] = v[c];
        }
      } else if (h == 0 && tid >= 512) {
        const int idx = tid - 512;                    // 0..255
        U11b[p*256 + idx] = pan[idx >> 4][idx & 15];
      }
    } else {
      if (h == 0 && tid == 0) U11b[16*256] = pan[0][0];
    }
    __syncthreads();
    // ---- 5. trailing rank-16 update, OWN columns: 64 col-pair lanes x 12 rowg ----
    if (pw == NB && ownCols > 0 && nrt > 0) {
      const int jp   = tid & 63;
      const int rowg = tid >> 6;                      // 0..11
      if (clo + 2*jp < chiC) {
        const int jrel = (clo - tc0) + 2*jp;          // even
        double va[NB], vb[NB];
#pragma unroll
        for (int c = 0; c < NB; c++) {
          double2 u = *(const double2*)&Ub[c][2*jp];
          va[c] = u.x; vb[c] = u.y;
        }
        auto loadrow = [&](int rr, double2& x0, double2& x1) {
          x0 = make_double2(0.0, 0.0); x1 = x0;
          if (rr < nrt) {
            const int row0 = tc0 + rr;
            const size_t ad = (size_t)row0*WROW + tc0 + jrel;
            x0 = *(const double2*)&Pb[ad];
            if (rr + 1 < nrt) x1 = *(const double2*)&Pb[ad + WROW];
            if (first) {
              if (two) {
                double2 q0 = *(const double2*)&Qb[ad]; x0.x += q0.x; x0.y += q0.y;
                if (rr + 1 < nrt) { double2 q1 = *(const double2*)&Qb[ad + WROW]; x1.x += q1.x; x1.y += q1.y; }
              }
              if (three) {
                double2 r0v = *(const double2*)&Rb[ad]; x0.x += r0v.x; x0.y += r0v.y;
                if (rr + 1 < nrt) { double2 r1v = *(const double2*)&Rb[ad + WROW]; x1.x += r1v.x; x1.y += r1v.y; }
              }
              if (rr == jrel) {
                const int row0g = tc0 + rr;
                if (row0g < NATOM) {
                  int z = znum[b*NATOM + row0g];
                  float Jr = (z == 1) ? J0 : (z == 6) ? J1 : (z == 7) ? J2 : J3;
                  x0.x += (double)Jr*(double)Jr - DIAG_SUB;
                }
                if (rr + 1 < nrt && row0g + 1 < NATOM) {
                  int z = znum[b*NATOM + row0g + 1];
                  float Jr = (z == 1) ? J0 : (z == 6) ? J1 : (z == 7) ? J2 : J3;
                  x1.y += (double)Jr*(double)Jr - DIAG_SUB;
                }
              }
            }
          }
        };
        int rr = 2*rowg;
        double2 a0, a1;
        loadrow(rr, a0, a1);
        while (rr < nrt) {
          const int rn = rr + 24;                     // 12 row-groups x 2 rows
          double2 n0, n1;
          loadrow(rn, n0, n1);
          const double* pr0 = pan[NB + rr];
          const double* pr1 = pan[NB + rr + 1];
#pragma unroll
          for (int m = 0; m < NB/2; m++) {
            double2 l0 = *(const double2*)&pr0[2*m];
            double2 l1 = *(const double2*)&pr1[2*m];
            a0.x -= l0.x*va[2*m] + l0.y*va[2*m+1];
            a0.y -= l0.x*vb[2*m] + l0.y*vb[2*m+1];
            a1.x -= l1.x*va[2*m] + l1.y*va[2*m+1];
            a1.y -= l1.x*vb[2*m] + l1.y*vb[2*m+1];
          }
          const size_t ad = (size_t)(tc0+rr)*WROW + tc0 + jrel;
          *(double2*)&Pb[ad] = a0;
          if (rr + 1 < nrt) *(double2*)&Pb[ad + WROW] = a1;
          a0 = n0; a1 = n1;
          rr = rn;
        }
      }
    }
    __syncthreads();
    // ---- raise own flag (release) ----
    if (pw == NB && tid == 0) {
      __threadfence();
      if (h == 0) atomicExch(&FA[p], 1);
      else        atomicExch(&FB[p], 1);
    }
  }
}

// ---------------- K4b (grid 8, block 256): backsolve + outputs ----------------
// U11 from scratch (U11g); U12 and swept rhs from Pb.
__global__ __launch_bounds__(BDB) void solve_back(
    double* __restrict__ P0g, const double* __restrict__ U11g,
    const void* __restrict__ c0, const void* __restrict__ c1, const void* __restrict__ c2,
    const float* __restrict__ Jraw, const float* __restrict__ syschg,
    float* __restrict__ out)
{
  const int b = blockIdx.x;
  const int tid = threadIdx.x;
  double* Pb = P0g + (size_t)b*NP1*WROW;
  const double* U11b = U11g + (size_t)b*17*256;

  __shared__ double panb[NB][NB+1];
  __shared__ double xs[NP1];
  __shared__ double red[BDB];

  const float* chi = nullptr; const int* znum = nullptr;
  classify2(c0, c1, c2, chi, znum);
  const double rhsN = (double)syschg[b] * sqrt(90.0474);
  const float J0 = Jraw[0], J1 = Jraw[1], J2 = Jraw[2], J3 = Jraw[3];

  for (int r = tid; r < NP1; r += BDB) xs[r] = Pb[(size_t)r*WROW + 257];
  __syncthreads();
  for (int pb0 = 256; pb0 >= 0; pb0 -= NB) {
    const int w = (pb0 == 256) ? 1 : NB;
    if (w == NB) {
      {
        const int i = tid >> 4, c = tid & 15;
        panb[i][c] = U11b[(pb0 >> 4)*256 + i*16 + c];
      }
      __syncthreads();
      if (tid < NB) {
        double u[NB];
#pragma unroll
        for (int c = 0; c < NB; c++) u[c] = panb[tid][c];
        double y  = xs[pb0 + tid];
        double di = 1.0 / panb[tid][tid];
        double xr = 0.0;
#pragma unroll
        for (int i = NB-1; i >= 0; i--) {
          double xi = y * di;
          xi = __shfl(xi, i);
          if (tid == i) xr = xi;
          if (tid < i)  y -= u[i] * xi;
        }
        xs[pb0 + tid] = xr;
      }
    } else {
      if (tid == 0) xs[256] = xs[256] / U11b[16*256];
    }
    __syncthreads();
    if (tid < pb0) {
      const double* rowp = &Pb[(size_t)tid*WROW + pb0];
      double s = 0.0;
      for (int c = 0; c < w; c++) s += rowp[c]*xs[pb0+c];
      xs[tid] -= s;
    }
    __syncthreads();
  }

  // ---- outputs: q + residual-identity energy ----
  out[b*NATOM + tid] = (float)xs[tid];
  const double lam = xs[NATOM];
  double q  = xs[tid];
  double ch = (double)chi[b*NATOM + tid];
  int z = znum[b*NATOM + tid];
  float Jr = (z == 1) ? J0 : (z == 6) ? J1 : (z == 7) ? J2 : J3;
  red[tid] = q*ch + (double)Jr*(double)Jr*q*q;
  __syncthreads();
  for (int st = BDB/2; st > 0; st >>= 1) {
    if (tid < st) red[tid] += red[tid + st];
    __syncthreads();
  }
  if (tid == 0)
    out[NBATCH*NATOM + b] = (float)(-0.5*(red[0] + lam*rhsN));
}

// ---------------- host launch ----------------
extern "C" void kernel_launch(void* const* d_in, const int* in_sizes, int n_in,
                              void* d_out, int out_size, void* d_ws, size_t ws_size,
                              hipStream_t stream)
{
  int iPos=-1, iCell=-1, iJ=-1, iQ=-1, cand[3]={-1,-1,-1}, nc=0;
  for (int i = 0; i < n_in; i++) {
    int s = in_sizes[i];
    if      (s == 6144) iPos  = i;
    else if (s == 72)   iCell = i;
    else if (s == 4)    iJ    = i;
    else if (s == 8)    iQ    = i;
    else if (s == 2048 && nc < 3) cand[nc++] = i;
  }
  if (!(iPos>=0 && iCell>=0 && iJ>=0 && iQ>=0 && nc>=2)) {
    iPos=iCell=iJ=iQ=-1; nc=0; cand[0]=cand[1]=cand[2]=-1;
    for (int i = 0; i < n_in; i++) {
      int s = in_sizes[i];
      if      (s == 24576) iPos  = i;
      else if (s == 288)   iCell = i;
      else if (s == 16)    iJ    = i;
      else if (s == 32)    iQ    = i;
      else if (s == 8192 && nc < 3) cand[nc++] = i;
    }
  }
  if (!(iPos>=0 && iCell>=0 && iJ>=0 && iQ>=0 && nc>=2)) {
    iPos=0; iCell=1; iJ=3; iQ=4; cand[0]=2; cand[1]=5; cand[2]=6; nc=3;
  }
  if (nc == 2) cand[2] = cand[1];

  const float* pos  = (const float*)d_in[iPos];
  const float* cell = (const float*)d_in[iCell];
  const float* Jraw = (const float*)d_in[iJ];
  const float* sysq = (const float*)d_in[iQ];
  const void*  c0   = d_in[cand[0]];
  const void*  c1   = d_in[cand[1]];
  const void*  c2   = d_in[cand[2]];
  float* out = (float*)d_out;

  // ws: [plane0][plane1][plane2][Tg][klist][kw][kcount]
  const size_t planeB = (size_t)NBATCH*NP1*WROW*sizeof(double);  // 4,243,584
  const size_t tgB = 2064384, klB = 327680, kwB = 163840;
  const size_t trigAll = tgB + klB + kwB + 64;
  int nplanes = (ws_size >= 3*planeB + trigAll) ? 3 :
                ((ws_size >= 2*planeB + trigAll) ? 2 : 1);

  char* ws = (char*)d_ws;
  double*  P0g = (double*)ws;
  double*  P1g = (nplanes > 1) ? (double*)(ws + planeB)   : P0g;
  double*  P2g = (nplanes > 2) ? (double*)(ws + 2*planeB) : P1g;
  char* trigBase = ws + (size_t)nplanes*planeB;
  double2* Tg     = (double2*)trigBase;
  int4*    klist  = (int4*)  (trigBase + tgB);
  double*  kwa    = (double*)(trigBase + tgB + klB);
  int*     kcount = (int*)   (trigBase + tgB + klB + kwB);
  double*  U11g   = (double*)trigBase;   // Tg region is dead after build_A; 278KB << 2MB

  hipLaunchKernelGGL(zero_planes,  dim3(512),           dim3(256), 0, stream,
                     P0g, klist, nplanes);
  hipLaunchKernelGGL(prep,         dim3(NBATCH),        dim3(256), 0, stream,
                     pos, cell, Tg, klist, kwa, kcount, c0, c1, c2, sysq,
                     P0g, nplanes);
  hipLaunchKernelGGL(build_A_gemm, dim3(160*nplanes),   dim3(256), 0, stream,
                     Tg, klist, kwa, kcount, P0g, P1g, P2g, nplanes);
  hipLaunchKernelGGL(solve_factor, dim3(2*NBATCH),      dim3(BDF), 0, stream,
                     P0g, P1g, P2g, nplanes, c0, c1, c2, Jraw, klist, U11g);
  hipLaunchKernelGGL(solve_back,   dim3(NBATCH),        dim3(BDB), 0, stream,
                     P0g, U11g, c0, c1, c2, Jraw, sysq, out);
}

// Round 14
// 542.305 us; speedup vs baseline: 1.2756x; 1.0899x over previous
//
#include <hip/hip_runtime.h>
#include <math.h>

#define NBATCH 8
#define NATOM  256
#define NP1    257
#define WROW   258
#define TOTALK 9261
#define KCAP   2560
#define KC     16
#define NB     16
#define UBW    124
#define BDF    768
#define BDB    256
#define FLAGOFF 2528          /* int4 slot where per-batch flags live in klist tail */
#define SLOTMAX 2500          /* prep never writes k-entries at/above this slot */

#define TWO_PI_D 6.283185307179586
#define DIAG_SUB 0.7978845608028654   /* 2/sqrt(2*pi) */

__device__ __constant__ int TI10[10] = {0,0,0,0,1,1,1,2,2,3};
__device__ __constant__ int TJ10[10] = {0,1,2,3,1,2,3,2,3,3};

struct GemmSh {
  int4   kn[KC];
  double kw[KC];
  double cI[KC][64], sI[KC][64];
  double cJ[KC][64], sJ[KC][64];
};

// HW fp64 atomic add (gfx90a+/gfx950); CAS fallback if builtin missing.
__device__ __forceinline__ void atomAddD(double* p, double v) {
#if defined(__has_builtin)
#if __has_builtin(__builtin_amdgcn_global_atomic_fadd_f64)
  __builtin_amdgcn_global_atomic_fadd_f64(p, v);
  return;
#endif
#endif
  unsigned long long* u = (unsigned long long*)p;
  unsigned long long old = *u, assumed;
  do {
    assumed = old;
    old = atomicCAS(u, assumed,
                    (unsigned long long)__double_as_longlong(
                        v + __longlong_as_double((long long)assumed)));
  } while (old != assumed);
}

__device__ __forceinline__ void classify2(const void* c0, const void* c1, const void* c2,
                                          const float*& chi, const int*& znum)
{
  const void* cands[3] = {c0, c1, c2};
  int got = 0;
  for (int i = 0; i < 3; i++) {
    unsigned uu = ((const unsigned*)cands[i])[0];
    if (uu == 0u) continue;                                      // batch
    else if (uu < 16u) { znum = (const int*)cands[i]; got |= 1; }// z in {1,6,7,8}
    else               { chi  = (const float*)cands[i]; got |= 2; }
  }
  if (got != 3) { chi = (const float*)c0; znum = (const int*)c1; }
}

// ---------------- K0 (grid 512): zero flags + (atomic path only) A-planes --------
__global__ __launch_bounds__(256) void zero_planes(
    double* __restrict__ P0g, int4* __restrict__ klist, int nzero)
{
  if (blockIdx.x == 0 && threadIdx.x < 256) {
    const int b = threadIdx.x >> 5, s = threadIdx.x & 31;
    klist[(size_t)b*KCAP + FLAGOFF + s] = make_int4(0, 0, 0, 0);
  }
  if (nzero <= 0) return;
  const size_t npair = (size_t)nzero * NBATCH * ((NP1*WROW) >> 1);
  double2* Z = (double2*)P0g;   // planes are contiguous
  const double2 z = make_double2(0.0, 0.0);
  for (size_t i = (size_t)blockIdx.x*256 + threadIdx.x; i < npair;
       i += (size_t)gridDim.x*256)
    Z[i] = z;
}

// ---------------- K1 (grid 8): trig tables + k-list + aug borders ----------------
__global__ __launch_bounds__(256) void prep(
    const float* __restrict__ pos, const float* __restrict__ cell,
    double2* __restrict__ Tg, int4* __restrict__ klist,
    double* __restrict__ kw, int* __restrict__ kcount,
    const void* __restrict__ c0, const void* __restrict__ c1, const void* __restrict__ c2,
    const float* __restrict__ syschg,
    double* __restrict__ P0g, double* __restrict__ P1g, double* __restrict__ P2g,
    int nplanes)
{
  const int b = blockIdx.x;
  const int tid = threadIdx.x;
  __shared__ double ivs[9];
  __shared__ double prefs;
  __shared__ int cnt;
  if (tid == 0) {
    double c[9];
#pragma unroll
    for (int i = 0; i < 9; i++) c[i] = (double)cell[b*9+i];
    double det = c[0]*(c[4]*c[8]-c[5]*c[7]) - c[1]*(c[3]*c[8]-c[5]*c[6])
               + c[2]*(c[3]*c[7]-c[4]*c[6]);
    double idet = 1.0/det;
    ivs[0]=(c[4]*c[8]-c[5]*c[7])*idet; ivs[1]=(c[2]*c[7]-c[1]*c[8])*idet; ivs[2]=(c[1]*c[5]-c[2]*c[4])*idet;
    ivs[3]=(c[5]*c[6]-c[3]*c[8])*idet; ivs[4]=(c[0]*c[8]-c[2]*c[6])*idet; ivs[5]=(c[2]*c[3]-c[0]*c[5])*idet;
    ivs[6]=(c[3]*c[7]-c[4]*c[6])*idet; ivs[7]=(c[1]*c[6]-c[0]*c[7])*idet; ivs[8]=(c[0]*c[4]-c[1]*c[3])*idet;
    prefs = 2.0*TWO_PI_D/fabs(det);
    cnt = 0;
  }
  __syncthreads();
  {
    const int a = tid;
    double x = (double)pos[((size_t)b*NATOM+a)*3+0];
    double y = (double)pos[((size_t)b*NATOM+a)*3+1];
    double z = (double)pos[((size_t)b*NATOM+a)*3+2];
    double u[3];
    u[0] = TWO_PI_D*(ivs[0]*x + ivs[3]*y + ivs[6]*z);
    u[1] = TWO_PI_D*(ivs[1]*x + ivs[4]*y + ivs[7]*z);
    u[2] = TWO_PI_D*(ivs[2]*x + ivs[5]*y + ivs[8]*z);
#pragma unroll
    for (int d = 0; d < 3; d++) {
      double2* T = Tg + (size_t)((b*3 + d)*21)*256;
      double c1 = cos(u[d]);
      double s1 = sin(u[d]);
      T[10*256 + a] = make_double2(1.0, 0.0);
      T[11*256 + a] = make_double2(c1,  s1);
      T[ 9*256 + a] = make_double2(c1, -s1);
      double cp = c1, sp = s1;
      for (int n = 2; n <= 10; n++) {
        double cn = cp*c1 - sp*s1;
        double sn = sp*c1 + cp*s1;
        cp = cn; sp = sn;
        T[(10+n)*256 + a] = make_double2(cp,  sp);
        T[(10-n)*256 + a] = make_double2(cp, -sp);
      }
    }
  }
  const double ksqmax = (TWO_PI_D/1.5)*(TWO_PI_D/1.5);
  for (int m = tid; m < TOTALK; m += 256) {
    int n1 = m/441 - 10;
    int n2 = (m/21)%21 - 10;
    int n3 = m%21 - 10;
    bool half = (n1 > 0) || (n1 == 0 && (n2 > 0 || (n2 == 0 && n3 > 0)));
    if (!half) continue;
    double d1 = n1, d2 = n2, d3 = n3;
    double kx = TWO_PI_D*(ivs[0]*d1 + ivs[1]*d2 + ivs[2]*d3);
    double ky = TWO_PI_D*(ivs[3]*d1 + ivs[4]*d2 + ivs[5]*d3);
    double kz = TWO_PI_D*(ivs[6]*d1 + ivs[7]*d2 + ivs[8]*d3);
    double k2 = kx*kx + ky*ky + kz*kz;
    if (k2 > 1e-10 && k2 < ksqmax) {
      double w = 2.0 * prefs * exp(-0.5*k2) / k2;
      int slot = atomicAdd(&cnt, 1);
      if (slot < SLOTMAX) {               // protect flag region (cnt ~2100 in practice)
        klist[b*KCAP + slot] = make_int4(n1, n2, n3, 0);
        kw[b*KCAP + slot] = w;
      }
    }
  }
  __syncthreads();   // k-list complete before kcount
  // aug borders: P0 real values; P1/P2 borders zeroed here (store path relies on it;
  // harmless after zero_planes in the atomic path)
  {
    const float* chi = nullptr; const int* znum = nullptr;
    classify2(c0, c1, c2, chi, znum);
    double* P0b = P0g + (size_t)b*NP1*WROW;
    double* P1b = P1g + (size_t)b*NP1*WROW;
    double* P2b = P2g + (size_t)b*NP1*WROW;
    for (int i = tid; i < NATOM; i += 256) {
      P0b[(size_t)NATOM*WROW + i] = 1.0;
      P0b[(size_t)i*WROW + NATOM] = 1.0;
      P0b[(size_t)i*WROW + 257]   = -(double)chi[b*NATOM + i];
      if (nplanes > 1) {
        P1b[(size_t)NATOM*WROW + i] = 0.0;
        P1b[(size_t)i*WROW + NATOM] = 0.0;
        P1b[(size_t)i*WROW + 257]   = 0.0;
      }
      if (nplanes > 2) {
        P2b[(size_t)NATOM*WROW + i] = 0.0;
        P2b[(size_t)i*WROW + NATOM] = 0.0;
        P2b[(size_t)i*WROW + 257]   = 0.0;
      }
    }
    if (tid == 0) {
      P0b[(size_t)NATOM*WROW + NATOM] = 0.0;
      P0b[(size_t)NATOM*WROW + 257]   = (double)syschg[b]*sqrt(90.0474);
      if (nplanes > 1) {
        P1b[(size_t)NATOM*WROW + NATOM] = 0.0;
        P1b[(size_t)NATOM*WROW + 257]   = 0.0;
      }
      if (nplanes > 2) {
        P2b[(size_t)NATOM*WROW + NATOM] = 0.0;
        P2b[(size_t)NATOM*WROW + 257]   = 0.0;
      }
      kcount[b] = (cnt < SLOTMAX) ? cnt : SLOTMAX;
    }
  }
}

// ---------------- fp64 tile GEMM into a plane (stores or atomic-accumulate) -----
__device__ void gemm_tile(int b, int ti, int tj, int tid,
                          const double2* __restrict__ Tg,
                          const int4* __restrict__ klist,
                          const double* __restrict__ kw, int ks, int ke,
                          double* __restrict__ Ab, bool mirror, bool useAtomic,
                          GemmSh& S)
{
  const int tx = tid & 15, ty = tid >> 4;
  const int ro = ty << 2, co = tx << 2;
  double acc[16];
#pragma unroll
  for (int i = 0; i < 16; i++) acc[i] = 0.0;

  for (int k0 = ks; k0 < ke; k0 += KC) {
    if (tid < KC) {
      int kk = k0 + tid;
      if (kk < ke) { S.kn[tid] = klist[b*KCAP + kk]; S.kw[tid] = kw[b*KCAP + kk]; }
      else         { S.kn[tid] = make_int4(0,0,0,0); S.kw[tid] = 0.0; }
    }
    __syncthreads();
#pragma unroll
    for (int p = 0; p < 8; p++) {
      int idx = p*256 + tid;
      int a    = idx & 63;
      int kk   = (idx >> 6) & (KC-1);
      int side = idx >> 10;
      int atom = ((side == 0) ? ti : tj) + a;
      int4 nn = S.kn[kk];
      double2 t1 = Tg[(size_t)((b*3+0)*21 + (nn.x+10))*256 + atom];
      double2 t2 = Tg[(size_t)((b*3+1)*21 + (nn.y+10))*256 + atom];
      double2 t3 = Tg[(size_t)((b*3+2)*21 + (nn.z+10))*256 + atom];
      double ex = t1.x*t2.x - t1.y*t2.y;
      double ey = t1.x*t2.y + t1.y*t2.x;
      double cx = ex*t3.x - ey*t3.y;
      double cy = ex*t3.y + ey*t3.x;
      if (side == 0) { double w = S.kw[kk]; S.cI[kk][a] = w*cx; S.sI[kk][a] = w*cy; }
      else           { S.cJ[kk][a] = cx; S.sJ[kk][a] = cy; }
    }
    __syncthreads();
#pragma unroll
    for (int kk = 0; kk < KC; kk++) {
      double ci[4], si[4], cj[4], sj[4];
#pragma unroll
      for (int r = 0; r < 2; r++) {
        double2 v0 = *(const double2*)&S.cI[kk][ro + 2*r];
        ci[2*r] = v0.x; ci[2*r+1] = v0.y;
        double2 v1 = *(const double2*)&S.sI[kk][ro + 2*r];
        si[2*r] = v1.x; si[2*r+1] = v1.y;
        double2 v2 = *(const double2*)&S.cJ[kk][co + 2*r];
        cj[2*r] = v2.x; cj[2*r+1] = v2.y;
        double2 v3 = *(const double2*)&S.sJ[kk][co + 2*r];
        sj[2*r] = v3.x; sj[2*r+1] = v3.y;
      }
#pragma unroll
      for (int r = 0; r < 4; r++)
#pragma unroll
        for (int c = 0; c < 4; c++)
          acc[r*4+c] += ci[r]*cj[c] + si[r]*sj[c];
    }
    __syncthreads();
  }
#pragma unroll
  for (int r = 0; r < 4; r++) {
#pragma unroll
    for (int c = 0; c < 4; c++) {
      int gr = ti + ro + r, gc = tj + co + c;
      double v = acc[r*4+c];
      if (useAtomic) {
        atomAddD(&Ab[(size_t)gr*WROW + gc], v);
        if (mirror && ti != tj) atomAddD(&Ab[(size_t)gc*WROW + gr], v);
      } else {
        Ab[(size_t)gr*WROW + gc] = v;
        if (mirror && ti != tj) Ab[(size_t)gc*WROW + gr] = v;
      }
    }
  }
}

// ---------------- K2 (grid 80*nseg): tiles x batches x k-segments ----------------
// accMode==0 (6-plane store path): nseg=6, each segment OWNS plane seg -> plain
// stores, no atomics, no zero-init (r10 measured the atomic tax: 2x atomics =
// +50us). accMode==1 (atomic fallback, r13 behavior): nseg=2*nplanes, segment
// accumulates into plane seg%nplanes via fp64 atomics (planes pre-zeroed).
__global__ __launch_bounds__(256) void build_A_gemm(
    const double2* __restrict__ Tg, const int4* __restrict__ klist,
    const double* __restrict__ kw, const int* __restrict__ kcount,
    double* __restrict__ P0g, double* __restrict__ P1g, double* __restrict__ P2g,
    double* __restrict__ P3g, double* __restrict__ P4g, double* __restrict__ P5g,
    int nplanes, int accMode)
{
  __shared__ GemmSh S;
  const int nseg = (accMode == 0) ? 6 : 2*nplanes;
  const int u = blockIdx.x;
  const int seg = u / 80;
  const int r = u - seg*80;
  const int b = r / 10;
  const int t = r - b*10;
  int s;
  double* base;
  if (accMode == 0) {
    s = seg;
    base = (s == 0) ? P0g : (s == 1) ? P1g : (s == 2) ? P2g
         : (s == 3) ? P3g : (s == 4) ? P4g : P5g;
  } else {
    s = (seg < nplanes) ? seg : (seg - nplanes);
    base = (s == 0) ? P0g : (s == 1) ? P1g : P2g;
  }
  const int cnt = kcount[b];
  const int ks = (int)((long long)cnt * seg / nseg);
  const int ke = (int)((long long)cnt * (seg+1) / nseg);
  double* Ab = base + (size_t)b*NP1*WROW;
  gemm_tile(b, TI10[t]*64, TJ10[t]*64, threadIdx.x, Tg, klist, kw, ks, ke, Ab,
            true, accMode != 0, S);
}

// ---------------- K2b (grid 512): fold P3..5 into P0..2 (interior 256x256 only) --
__global__ __launch_bounds__(256) void merge_planes(double* __restrict__ P0g)
{
  const size_t per = (size_t)NP1*WROW >> 1;        // 33153 double2 per (plane,batch)
  double2* B = (double2*)P0g;
  const size_t nwork = (size_t)3*NBATCH*256*128;   // 3 plane-pairs x 8 b x 256 r x 128 c2
  for (size_t i = (size_t)blockIdx.x*256 + threadIdx.x; i < nwork;
       i += (size_t)gridDim.x*256) {
    const int c2 = (int)(i & 127);
    size_t t = i >> 7;
    const int rr = (int)(t & 255);
    const int pb = (int)(t >> 8);                  // (plane*8 + batch), 0..23
    const size_t d = (size_t)pb*per + (size_t)rr*129 + c2;
    const size_t sidx = d + 24*per;                // planes 3..5 follow 0..2
    double2 a = B[d];
    const double2 x = B[sidx];
    a.x += x.x; a.y += x.y;
    B[d] = a;
  }
}

// ---------------- K4a (grid 16, block 768): column-split no-pivot LU factor -----
// BYTE-IDENTICAL to the round-13 banked version (285us, passing).
__global__ __launch_bounds__(BDF, 2) void solve_factor(
    double* __restrict__ P0g, const double* __restrict__ P1g, const double* __restrict__ P2g,
    int nplanes,
    const void* __restrict__ c0, const void* __restrict__ c1, const void* __restrict__ c2,
    const float* __restrict__ Jraw,
    int4* __restrict__ klist, double* __restrict__ U11g)
{
  const int b = blockIdx.x >> 1;
  const int h = blockIdx.x & 1;
  const int tid = threadIdx.x;
  double* Pb = P0g + (size_t)b*NP1*WROW;
  const double* Qb = P1g + (size_t)b*NP1*WROW;
  const double* Rb = P2g + (size_t)b*NP1*WROW;
  const bool two   = (nplanes > 1);
  const bool three = (nplanes > 2);
  int* FA = (int*)(klist + (size_t)b*KCAP + FLAGOFF);   // FA[p]: h0 done panel p
  int* FB = FA + 32;                                     // FB[p]: h1 done panel p
  double* U11b = U11g + (size_t)b*17*256;

  __shared__ __align__(16) double pan[NP1+4][NB+2];
  __shared__ double dnv[NB];
  __shared__ __align__(16) double Ub[NB][UBW];

  const float* chi = nullptr; const int* znum = nullptr;
  classify2(c0, c1, c2, chi, znum);
  const float J0 = Jraw[0], J1 = Jraw[1], J2 = Jraw[2], J3 = Jraw[3];

  int p = 0;
  for (int p0 = 0; p0 < NP1; p0 += NB, p++) {
    const int pw  = (NB < NP1 - p0) ? NB : (NP1 - p0);
    const int nr  = NP1 - p0;
    const int nrt = nr - pw;
    const int tc0 = p0 + pw;
    const int tc  = WROW - tc0;                         // even
    const bool first = (p0 == 0);
    int leftCols = (tc >= 4) ? (((tc >> 1) + 1) & ~1) : tc;
    const int clo = (h == 0) ? tc0 : tc0 + leftCols;
    const int chiC = (h == 0) ? tc0 + leftCols : tc0 + tc;
    const int ownCols = chiC - clo;
    if (p > 0) {
      if (tid == 0) {
        while (atomicAdd(&FA[p-1], 0) == 0) __builtin_amdgcn_s_sleep(2);
        while (atomicAdd(&FB[p-1], 0) == 0) __builtin_amdgcn_s_sleep(2);
        __threadfence();
      }
      __syncthreads();
    }
    for (int idx = tid; idx < nr*pw; idx += BDF) {
      int r, c;
      if (pw == NB) { r = idx >> 4; c = idx & 15; } else { r = idx; c = 0; }
      double v;
      if (first) {
        size_t a = (size_t)r*WROW + c;
        v = Pb[a];
        if (two)   v += Qb[a];
        if (three) v += Rb[a];
        if (r == c) {
          int z = znum[b*NATOM + r];
          float Jr = (z == 1) ? J0 : (z == 6) ? J1 : (z == 7) ? J2 : J3;
          v += (double)Jr*(double)Jr - DIAG_SUB;
        }
      } else {
        v = Pb[(size_t)(p0+r)*WROW + p0 + c];
      }
      pan[r][c] = v;
    }
    __syncthreads();
    if (pw == NB) {
      if (tid < NB) {
        double v[NB];
#pragma unroll
        for (int c = 0; c < NB; c++) v[c] = pan[tid][c];
#pragma unroll
        for (int c = 0; c < NB; c++) {
          double piv = __shfl(v[c], c);
          double dinv = 1.0 / piv;
          if (tid == c) dnv[c] = dinv;
          double f = v[c] * dinv;
#pragma unroll
          for (int cc = 0; cc < NB; cc++) {
            if (cc > c) {
              double ucc = __shfl(v[cc], c);
              if (tid > c) v[cc] -= f * ucc;
            }
          }
          if (tid > c) v[c] = f;
        }
#pragma unroll
        for (int c = 0; c < NB; c++) pan[tid][c] = v[c];
      }
    }
    __syncthreads();
    if (pw == NB) {
      if (tid < nrt) {
        const int r = NB + tid;
        double w[NB];
#pragma unroll
        for (int c = 0; c < NB; c++) w[c] = pan[r][c];
#pragma unroll
        for (int c = 0; c < NB; c++) {
          double s = w[c];
#pragma unroll
          for (int c2 = 0; c2 < NB; c2++) if (c2 < c) s -= w[c2] * pan[c2][c];
          w[c] = s * dnv[c];
        }
#pragma unroll
        for (int c = 0; c < NB; c++) pan[r][c] = w[c];
      } else if (tid >= 256 && tid < 256 + ownCols) {
        const int j = clo + (tid - 256);
        double v[NB];
#pragma unroll
        for (int c = 0; c < NB; c++) {
          size_t a = (size_t)(p0+c)*WROW + j;
          double t = Pb[a];
          if (first) {
            if (two)   t += Qb[a];
            if (three) t += Rb[a];
          }
          v[c] = t;
        }
#pragma unroll
        for (int c = 0; c < NB; c++)
#pragma unroll
          for (int r2 = 0; r2 < NB; r2++) if (r2 > c) v[r2] -= pan[r2][c]*v[c];
#pragma unroll
        for (int c = 0; c < NB; c++) {
          Pb[(size_t)(p0+c)*WROW + j] = v[c];
          Ub[c][tid - 256] = v[c];
        }
      } else if (h == 0 && tid >= 512) {
        const int idx = tid - 512;                    // 0..255
        U11b[p*256 + idx] = pan[idx >> 4][idx & 15];
      }
    } else {
      if (h == 0 && tid == 0) U11b[16*256] = pan[0][0];
    }
    __syncthreads();
    if (pw == NB && ownCols > 0 && nrt > 0) {
      const int jp   = tid & 63;
      const int rowg = tid >> 6;                      // 0..11
      if (clo + 2*jp < chiC) {
        const int jrel = (clo - tc0) + 2*jp;          // even
        double va[NB], vb[NB];
#pragma unroll
        for (int c = 0; c < NB; c++) {
          double2 u = *(const double2*)&Ub[c][2*jp];
          va[c] = u.x; vb[c] = u.y;
        }
        auto loadrow = [&](int rr, double2& x0, double2& x1) {
          x0 = make_double2(0.0, 0.0); x1 = x0;
          if (rr < nrt) {
            const int row0 = tc0 + rr;
            const size_t ad = (size_t)row0*WROW + tc0 + jrel;
            x0 = *(const double2*)&Pb[ad];
            if (rr + 1 < nrt) x1 = *(const double2*)&Pb[ad + WROW];
            if (first) {
              if (two) {
                double2 q0 = *(const double2*)&Qb[ad]; x0.x += q0.x; x0.y += q0.y;
                if (rr + 1 < nrt) { double2 q1 = *(const double2*)&Qb[ad + WROW]; x1.x += q1.x; x1.y += q1.y; }
              }
              if (three) {
                double2 r0v = *(const double2*)&Rb[ad]; x0.x += r0v.x; x0.y += r0v.y;
                if (rr + 1 < nrt) { double2 r1v = *(const double2*)&Rb[ad + WROW]; x1.x += r1v.x; x1.y += r1v.y; }
              }
              if (rr == jrel) {
                const int row0g = tc0 + rr;
                if (row0g < NATOM) {
                  int z = znum[b*NATOM + row0g];
                  float Jr = (z == 1) ? J0 : (z == 6) ? J1 : (z == 7) ? J2 : J3;
                  x0.x += (double)Jr*(double)Jr - DIAG_SUB;
                }
                if (rr + 1 < nrt && row0g + 1 < NATOM) {
                  int z = znum[b*NATOM + row0g + 1];
                  float Jr = (z == 1) ? J0 : (z == 6) ? J1 : (z == 7) ? J2 : J3;
                  x1.y += (double)Jr*(double)Jr - DIAG_SUB;
                }
              }
            }
          }
        };
        int rr = 2*rowg;
        double2 a0, a1;
        loadrow(rr, a0, a1);
        while (rr < nrt) {
          const int rn = rr + 24;                     // 12 row-groups x 2 rows
          double2 n0, n1;
          loadrow(rn, n0, n1);
          const double* pr0 = pan[NB + rr];
          const double* pr1 = pan[NB + rr + 1];
#pragma unroll
          for (int m = 0; m < NB/2; m++) {
            double2 l0 = *(const double2*)&pr0[2*m];
            double2 l1 = *(const double2*)&pr1[2*m];
            a0.x -= l0.x*va[2*m] + l0.y*va[2*m+1];
            a0.y -= l0.x*vb[2*m] + l0.y*vb[2*m+1];
            a1.x -= l1.x*va[2*m] + l1.y*va[2*m+1];
            a1.y -= l1.x*vb[2*m] + l1.y*vb[2*m+1];
          }
          const size_t ad = (size_t)(tc0+rr)*WROW + tc0 + jrel;
          *(double2*)&Pb[ad] = a0;
          if (rr + 1 < nrt) *(double2*)&Pb[ad + WROW] = a1;
          a0 = n0; a1 = n1;
          rr = rn;
        }
      }
    }
    __syncthreads();
    if (pw == NB && tid == 0) {
      __threadfence();
      if (h == 0) atomicExch(&FA[p], 1);
      else        atomicExch(&FB[p], 1);
    }
  }
}

// ---------------- K4b (grid 8, block 256): backsolve + outputs ----------------
__global__ __launch_bounds__(BDB) void solve_back(
    double* __restrict__ P0g, const double* __restrict__ U11g,
    const void* __restrict__ c0, const void* __restrict__ c1, const void* __restrict__ c2,
    const float* __restrict__ Jraw, const float* __restrict__ syschg,
    float* __restrict__ out)
{
  const int b = blockIdx.x;
  const int tid = threadIdx.x;
  double* Pb = P0g + (size_t)b*NP1*WROW;
  const double* U11b = U11g + (size_t)b*17*256;

  __shared__ double panb[NB][NB+1];
  __shared__ double xs[NP1];
  __shared__ double red[BDB];

  const float* chi = nullptr; const int* znum = nullptr;
  classify2(c0, c1, c2, chi, znum);
  const double rhsN = (double)syschg[b] * sqrt(90.0474);
  const float J0 = Jraw[0], J1 = Jraw[1], J2 = Jraw[2], J3 = Jraw[3];

  for (int r = tid; r < NP1; r += BDB) xs[r] = Pb[(size_t)r*WROW + 257];
  __syncthreads();
  for (int pb0 = 256; pb0 >= 0; pb0 -= NB) {
    const int w = (pb0 == 256) ? 1 : NB;
    if (w == NB) {
      {
        const int i = tid >> 4, c = tid & 15;
        panb[i][c] = U11b[(pb0 >> 4)*256 + i*16 + c];
      }
      __syncthreads();
      if (tid < NB) {
        double u[NB];
#pragma unroll
        for (int c = 0; c < NB; c++) u[c] = panb[tid][c];
        double y  = xs[pb0 + tid];
        double di = 1.0 / panb[tid][tid];
        double xr = 0.0;
#pragma unroll
        for (int i = NB-1; i >= 0; i--) {
          double xi = y * di;
          xi = __shfl(xi, i);
          if (tid == i) xr = xi;
          if (tid < i)  y -= u[i] * xi;
        }
        xs[pb0 + tid] = xr;
      }
    } else {
      if (tid == 0) xs[256] = xs[256] / U11b[16*256];
    }
    __syncthreads();
    if (tid < pb0) {
      const double* rowp = &Pb[(size_t)tid*WROW + pb0];
      double s = 0.0;
      for (int c = 0; c < w; c++) s += rowp[c]*xs[pb0+c];
      xs[tid] -= s;
    }
    __syncthreads();
  }

  // ---- outputs: q + residual-identity energy ----
  out[b*NATOM + tid] = (float)xs[tid];
  const double lam = xs[NATOM];
  double q  = xs[tid];
  double ch = (double)chi[b*NATOM + tid];
  int z = znum[b*NATOM + tid];
  float Jr = (z == 1) ? J0 : (z == 6) ? J1 : (z == 7) ? J2 : J3;
  red[tid] = q*ch + (double)Jr*(double)Jr*q*q;
  __syncthreads();
  for (int st = BDB/2; st > 0; st >>= 1) {
    if (tid < st) red[tid] += red[tid + st];
    __syncthreads();
  }
  if (tid == 0)
    out[NBATCH*NATOM + b] = (float)(-0.5*(red[0] + lam*rhsN));
}

// ---------------- host launch ----------------
extern "C" void kernel_launch(void* const* d_in, const int* in_sizes, int n_in,
                              void* d_out, int out_size, void* d_ws, size_t ws_size,
                              hipStream_t stream)
{
  int iPos=-1, iCell=-1, iJ=-1, iQ=-1, cand[3]={-1,-1,-1}, nc=0;
  for (int i = 0; i < n_in; i++) {
    int s = in_sizes[i];
    if      (s == 6144) iPos  = i;
    else if (s == 72)   iCell = i;
    else if (s == 4)    iJ    = i;
    else if (s == 8)    iQ    = i;
    else if (s == 2048 && nc < 3) cand[nc++] = i;
  }
  if (!(iPos>=0 && iCell>=0 && iJ>=0 && iQ>=0 && nc>=2)) {
    iPos=iCell=iJ=iQ=-1; nc=0; cand[0]=cand[1]=cand[2]=-1;
    for (int i = 0; i < n_in; i++) {
      int s = in_sizes[i];
      if      (s == 24576) iPos  = i;
      else if (s == 288)   iCell = i;
      else if (s == 16)    iJ    = i;
      else if (s == 32)    iQ    = i;
      else if (s == 8192 && nc < 3) cand[nc++] = i;
    }
  }
  if (!(iPos>=0 && iCell>=0 && iJ>=0 && iQ>=0 && nc>=2)) {
    iPos=0; iCell=1; iJ=3; iQ=4; cand[0]=2; cand[1]=5; cand[2]=6; nc=3;
  }
  if (nc == 2) cand[2] = cand[1];

  const float* pos  = (const float*)d_in[iPos];
  const float* cell = (const float*)d_in[iCell];
  const float* Jraw = (const float*)d_in[iJ];
  const float* sysq = (const float*)d_in[iQ];
  const void*  c0   = d_in[cand[0]];
  const void*  c1   = d_in[cand[1]];
  const void*  c2   = d_in[cand[2]];
  float* out = (float*)d_out;

  // ws: [plane0..planeN-1][Tg][klist][kw][kcount]
  const size_t planeB = (size_t)NBATCH*NP1*WROW*sizeof(double);  // 4,243,584
  const size_t tgB = 2064384, klB = 327680, kwB = 163840;
  const size_t trigAll = tgB + klB + kwB + 64;
  int nacc;                       // accumulation planes allocated
  if      (ws_size >= 6*planeB + trigAll) nacc = 6;   // store path (no atomics)
  else if (ws_size >= 3*planeB + trigAll) nacc = 3;   // atomic path (r13)
  else if (ws_size >= 2*planeB + trigAll) nacc = 2;
  else                                    nacc = 1;
  const int nplanes = (nacc >= 3) ? 3 : nacc;         // planes the factor sums
  const int accMode = (nacc == 6) ? 0 : 1;            // 0 = store, 1 = atomic

  char* ws = (char*)d_ws;
  double*  P0g = (double*)ws;
  double*  P1g = (nacc > 1) ? (double*)(ws + planeB)   : P0g;
  double*  P2g = (nacc > 2) ? (double*)(ws + 2*planeB) : P1g;
  double*  P3g = (nacc > 3) ? (double*)(ws + 3*planeB) : P0g;
  double*  P4g = (nacc > 4) ? (double*)(ws + 4*planeB) : P0g;
  double*  P5g = (nacc > 5) ? (double*)(ws + 5*planeB) : P0g;
  char* trigBase = ws + (size_t)nacc*planeB;
  double2* Tg     = (double2*)trigBase;
  int4*    klist  = (int4*)  (trigBase + tgB);
  double*  kwa    = (double*)(trigBase + tgB + klB);
  int*     kcount = (int*)   (trigBase + tgB + klB + kwB);
  double*  U11g   = (double*)trigBase;   // Tg region dead after build_A; 278KB << 2MB

  const int nseg = (accMode == 0) ? 6 : 2*nplanes;

  hipLaunchKernelGGL(zero_planes,  dim3(512),       dim3(256), 0, stream,
                     P0g, klist, (accMode == 1) ? nplanes : 0);
  hipLaunchKernelGGL(prep,         dim3(NBATCH),    dim3(256), 0, stream,
                     pos, cell, Tg, klist, kwa, kcount, c0, c1, c2, sysq,
                     P0g, P1g, P2g, nplanes);
  hipLaunchKernelGGL(build_A_gemm, dim3(80*nseg),   dim3(256), 0, stream,
                     Tg, klist, kwa, kcount, P0g, P1g, P2g, P3g, P4g, P5g,
                     nplanes, accMode);
  if (accMode == 0)
    hipLaunchKernelGGL(merge_planes, dim3(512),     dim3(256), 0, stream, P0g);
  hipLaunchKernelGGL(solve_factor, dim3(2*NBATCH),  dim3(BDF), 0, stream,
                     P0g, P1g, P2g, nplanes, c0, c1, c2, Jraw, klist, U11g);
  hipLaunchKernelGGL(solve_back,   dim3(NBATCH),    dim3(BDB), 0, stream,
                     P0g, U11g, c0, c1, c2, Jraw, sysq, out);
}

// Round 15
// 533.576 us; speedup vs baseline: 1.2965x; 1.0164x over previous
//
#include <hip/hip_runtime.h>
#include <math.h>

#define NBATCH 8
#define NATOM  256
#define NP1    257
#define WROW   258
#define TOTALK 9261
#define KCAP   2560
#define KC     16
#define NB     16
#define UBW    124
#define BDF    768
#define BDB    256
#define FLAGOFF 2528          /* int4 slot where per-batch flags live in klist tail */
#define SLOTMAX 2500          /* prep never writes k-entries at/above this slot */

#define TWO_PI_D 6.283185307179586
#define DIAG_SUB 0.7978845608028654   /* 2/sqrt(2*pi) */

__device__ __constant__ int TI10[10] = {0,0,0,0,1,1,1,2,2,3};
__device__ __constant__ int TJ10[10] = {0,1,2,3,1,2,3,2,3,3};

struct GemmSh {
  int4   kn[KC];
  double kw[KC];
  double cI[KC][64], sI[KC][64];
  double cJ[KC][64], sJ[KC][64];
};

// HW fp64 atomic add (gfx90a+/gfx950); CAS fallback if builtin missing.
__device__ __forceinline__ void atomAddD(double* p, double v) {
#if defined(__has_builtin)
#if __has_builtin(__builtin_amdgcn_global_atomic_fadd_f64)
  __builtin_amdgcn_global_atomic_fadd_f64(p, v);
  return;
#endif
#endif
  unsigned long long* u = (unsigned long long*)p;
  unsigned long long old = *u, assumed;
  do {
    assumed = old;
    old = atomicCAS(u, assumed,
                    (unsigned long long)__double_as_longlong(
                        v + __longlong_as_double((long long)assumed)));
  } while (old != assumed);
}

__device__ __forceinline__ void classify2(const void* c0, const void* c1, const void* c2,
                                          const float*& chi, const int*& znum)
{
  const void* cands[3] = {c0, c1, c2};
  int got = 0;
  for (int i = 0; i < 3; i++) {
    unsigned uu = ((const unsigned*)cands[i])[0];
    if (uu == 0u) continue;                                      // batch
    else if (uu < 16u) { znum = (const int*)cands[i]; got |= 1; }// z in {1,6,7,8}
    else               { chi  = (const float*)cands[i]; got |= 2; }
  }
  if (got != 3) { chi = (const float*)c0; znum = (const int*)c1; }
}

// ---------------- K0 (grid 512): zero flags + (atomic path only) A-planes --------
__global__ __launch_bounds__(256) void zero_planes(
    double* __restrict__ P0g, int4* __restrict__ klist, int nzero)
{
  if (blockIdx.x == 0 && threadIdx.x < 256) {
    const int b = threadIdx.x >> 5, s = threadIdx.x & 31;
    klist[(size_t)b*KCAP + FLAGOFF + s] = make_int4(0, 0, 0, 0);
  }
  if (nzero <= 0) return;
  const size_t npair = (size_t)nzero * NBATCH * ((NP1*WROW) >> 1);
  double2* Z = (double2*)P0g;   // planes are contiguous
  const double2 z = make_double2(0.0, 0.0);
  for (size_t i = (size_t)blockIdx.x*256 + threadIdx.x; i < npair;
       i += (size_t)gridDim.x*256)
    Z[i] = z;
}

// ---------------- K1 (grid 8): trig tables + k-list + aug borders ----------------
__global__ __launch_bounds__(256) void prep(
    const float* __restrict__ pos, const float* __restrict__ cell,
    double2* __restrict__ Tg, int4* __restrict__ klist,
    double* __restrict__ kw, int* __restrict__ kcount,
    const void* __restrict__ c0, const void* __restrict__ c1, const void* __restrict__ c2,
    const float* __restrict__ syschg,
    double* __restrict__ P0g, double* __restrict__ P1g, double* __restrict__ P2g,
    int nplanes)
{
  const int b = blockIdx.x;
  const int tid = threadIdx.x;
  __shared__ double ivs[9];
  __shared__ double prefs;
  __shared__ int cnt;
  if (tid == 0) {
    double c[9];
#pragma unroll
    for (int i = 0; i < 9; i++) c[i] = (double)cell[b*9+i];
    double det = c[0]*(c[4]*c[8]-c[5]*c[7]) - c[1]*(c[3]*c[8]-c[5]*c[6])
               + c[2]*(c[3]*c[7]-c[4]*c[6]);
    double idet = 1.0/det;
    ivs[0]=(c[4]*c[8]-c[5]*c[7])*idet; ivs[1]=(c[2]*c[7]-c[1]*c[8])*idet; ivs[2]=(c[1]*c[5]-c[2]*c[4])*idet;
    ivs[3]=(c[5]*c[6]-c[3]*c[8])*idet; ivs[4]=(c[0]*c[8]-c[2]*c[6])*idet; ivs[5]=(c[2]*c[3]-c[0]*c[5])*idet;
    ivs[6]=(c[3]*c[7]-c[4]*c[6])*idet; ivs[7]=(c[1]*c[6]-c[0]*c[7])*idet; ivs[8]=(c[0]*c[4]-c[1]*c[3])*idet;
    prefs = 2.0*TWO_PI_D/fabs(det);
    cnt = 0;
  }
  __syncthreads();
  {
    const int a = tid;
    double x = (double)pos[((size_t)b*NATOM+a)*3+0];
    double y = (double)pos[((size_t)b*NATOM+a)*3+1];
    double z = (double)pos[((size_t)b*NATOM+a)*3+2];
    double u[3];
    u[0] = TWO_PI_D*(ivs[0]*x + ivs[3]*y + ivs[6]*z);
    u[1] = TWO_PI_D*(ivs[1]*x + ivs[4]*y + ivs[7]*z);
    u[2] = TWO_PI_D*(ivs[2]*x + ivs[5]*y + ivs[8]*z);
#pragma unroll
    for (int d = 0; d < 3; d++) {
      double2* T = Tg + (size_t)((b*3 + d)*21)*256;
      double c1 = cos(u[d]);
      double s1 = sin(u[d]);
      T[10*256 + a] = make_double2(1.0, 0.0);
      T[11*256 + a] = make_double2(c1,  s1);
      T[ 9*256 + a] = make_double2(c1, -s1);
      double cp = c1, sp = s1;
      for (int n = 2; n <= 10; n++) {
        double cn = cp*c1 - sp*s1;
        double sn = sp*c1 + cp*s1;
        cp = cn; sp = sn;
        T[(10+n)*256 + a] = make_double2(cp,  sp);
        T[(10-n)*256 + a] = make_double2(cp, -sp);
      }
    }
  }
  const double ksqmax = (TWO_PI_D/1.5)*(TWO_PI_D/1.5);
  for (int m = tid; m < TOTALK; m += 256) {
    int n1 = m/441 - 10;
    int n2 = (m/21)%21 - 10;
    int n3 = m%21 - 10;
    bool half = (n1 > 0) || (n1 == 0 && (n2 > 0 || (n2 == 0 && n3 > 0)));
    if (!half) continue;
    double d1 = n1, d2 = n2, d3 = n3;
    double kx = TWO_PI_D*(ivs[0]*d1 + ivs[1]*d2 + ivs[2]*d3);
    double ky = TWO_PI_D*(ivs[3]*d1 + ivs[4]*d2 + ivs[5]*d3);
    double kz = TWO_PI_D*(ivs[6]*d1 + ivs[7]*d2 + ivs[8]*d3);
    double k2 = kx*kx + ky*ky + kz*kz;
    if (k2 > 1e-10 && k2 < ksqmax) {
      double w = 2.0 * prefs * exp(-0.5*k2) / k2;
      int slot = atomicAdd(&cnt, 1);
      if (slot < SLOTMAX) {               // protect flag region (cnt ~2100 in practice)
        klist[b*KCAP + slot] = make_int4(n1, n2, n3, 0);
        kw[b*KCAP + slot] = w;
      }
    }
  }
  __syncthreads();   // k-list complete before kcount
  // aug borders: P0 real values; P1/P2 borders zeroed here (store path relies on it;
  // harmless after zero_planes in the atomic path)
  {
    const float* chi = nullptr; const int* znum = nullptr;
    classify2(c0, c1, c2, chi, znum);
    double* P0b = P0g + (size_t)b*NP1*WROW;
    double* P1b = P1g + (size_t)b*NP1*WROW;
    double* P2b = P2g + (size_t)b*NP1*WROW;
    for (int i = tid; i < NATOM; i += 256) {
      P0b[(size_t)NATOM*WROW + i] = 1.0;
      P0b[(size_t)i*WROW + NATOM] = 1.0;
      P0b[(size_t)i*WROW + 257]   = -(double)chi[b*NATOM + i];
      if (nplanes > 1) {
        P1b[(size_t)NATOM*WROW + i] = 0.0;
        P1b[(size_t)i*WROW + NATOM] = 0.0;
        P1b[(size_t)i*WROW + 257]   = 0.0;
      }
      if (nplanes > 2) {
        P2b[(size_t)NATOM*WROW + i] = 0.0;
        P2b[(size_t)i*WROW + NATOM] = 0.0;
        P2b[(size_t)i*WROW + 257]   = 0.0;
      }
    }
    if (tid == 0) {
      P0b[(size_t)NATOM*WROW + NATOM] = 0.0;
      P0b[(size_t)NATOM*WROW + 257]   = (double)syschg[b]*sqrt(90.0474);
      if (nplanes > 1) {
        P1b[(size_t)NATOM*WROW + NATOM] = 0.0;
        P1b[(size_t)NATOM*WROW + 257]   = 0.0;
      }
      if (nplanes > 2) {
        P2b[(size_t)NATOM*WROW + NATOM] = 0.0;
        P2b[(size_t)NATOM*WROW + 257]   = 0.0;
      }
      kcount[b] = (cnt < SLOTMAX) ? cnt : SLOTMAX;
    }
  }
}

// ---------------- fp64 tile GEMM into a plane (stores or atomic-accumulate) -----
__device__ void gemm_tile(int b, int ti, int tj, int tid,
                          const double2* __restrict__ Tg,
                          const int4* __restrict__ klist,
                          const double* __restrict__ kw, int ks, int ke,
                          double* __restrict__ Ab, bool mirror, bool useAtomic,
                          GemmSh& S)
{
  const int tx = tid & 15, ty = tid >> 4;
  const int ro = ty << 2, co = tx << 2;
  double acc[16];
#pragma unroll
  for (int i = 0; i < 16; i++) acc[i] = 0.0;

  for (int k0 = ks; k0 < ke; k0 += KC) {
    if (tid < KC) {
      int kk = k0 + tid;
      if (kk < ke) { S.kn[tid] = klist[b*KCAP + kk]; S.kw[tid] = kw[b*KCAP + kk]; }
      else         { S.kn[tid] = make_int4(0,0,0,0); S.kw[tid] = 0.0; }
    }
    __syncthreads();
#pragma unroll
    for (int p = 0; p < 8; p++) {
      int idx = p*256 + tid;
      int a    = idx & 63;
      int kk   = (idx >> 6) & (KC-1);
      int side = idx >> 10;
      int atom = ((side == 0) ? ti : tj) + a;
      int4 nn = S.kn[kk];
      double2 t1 = Tg[(size_t)((b*3+0)*21 + (nn.x+10))*256 + atom];
      double2 t2 = Tg[(size_t)((b*3+1)*21 + (nn.y+10))*256 + atom];
      double2 t3 = Tg[(size_t)((b*3+2)*21 + (nn.z+10))*256 + atom];
      double ex = t1.x*t2.x - t1.y*t2.y;
      double ey = t1.x*t2.y + t1.y*t2.x;
      double cx = ex*t3.x - ey*t3.y;
      double cy = ex*t3.y + ey*t3.x;
      if (side == 0) { double w = S.kw[kk]; S.cI[kk][a] = w*cx; S.sI[kk][a] = w*cy; }
      else           { S.cJ[kk][a] = cx; S.sJ[kk][a] = cy; }
    }
    __syncthreads();
#pragma unroll
    for (int kk = 0; kk < KC; kk++) {
      double ci[4], si[4], cj[4], sj[4];
#pragma unroll
      for (int r = 0; r < 2; r++) {
        double2 v0 = *(const double2*)&S.cI[kk][ro + 2*r];
        ci[2*r] = v0.x; ci[2*r+1] = v0.y;
        double2 v1 = *(const double2*)&S.sI[kk][ro + 2*r];
        si[2*r] = v1.x; si[2*r+1] = v1.y;
        double2 v2 = *(const double2*)&S.cJ[kk][co + 2*r];
        cj[2*r] = v2.x; cj[2*r+1] = v2.y;
        double2 v3 = *(const double2*)&S.sJ[kk][co + 2*r];
        sj[2*r] = v3.x; sj[2*r+1] = v3.y;
      }
#pragma unroll
      for (int r = 0; r < 4; r++)
#pragma unroll
        for (int c = 0; c < 4; c++)
          acc[r*4+c] += ci[r]*cj[c] + si[r]*sj[c];
    }
    __syncthreads();
  }
#pragma unroll
  for (int r = 0; r < 4; r++) {
#pragma unroll
    for (int c = 0; c < 4; c++) {
      int gr = ti + ro + r, gc = tj + co + c;
      double v = acc[r*4+c];
      if (useAtomic) {
        atomAddD(&Ab[(size_t)gr*WROW + gc], v);
        if (mirror && ti != tj) atomAddD(&Ab[(size_t)gc*WROW + gr], v);
      } else {
        Ab[(size_t)gr*WROW + gc] = v;
        if (mirror && ti != tj) Ab[(size_t)gc*WROW + gr] = v;
      }
    }
  }
}

// ---------------- K2 (grid 80*nseg): tiles x batches x k-segments ----------------
// accMode==0 (store path): nseg = nacc (6 or 12), segment s OWNS plane s -> plain
// stores, no atomics, no zero-init. 12 planes => 960 blocks ~3.75/CU co-resident
// (r10's 12-way regression was the ATOMIC tax, removed here).
// accMode==1 (atomic fallback, r13): nseg=2*nplanes, fp64-atomic accumulate.
__global__ __launch_bounds__(256) void build_A_gemm(
    const double2* __restrict__ Tg, const int4* __restrict__ klist,
    const double* __restrict__ kw, const int* __restrict__ kcount,
    double* __restrict__ P0g, int nplanes, int accMode, int nseg)
{
  __shared__ GemmSh S;
  const int u = blockIdx.x;
  const int seg = u / 80;
  const int r = u - seg*80;
  const int b = r / 10;
  const int t = r - b*10;
  const size_t planeD = (size_t)NBATCH*NP1*WROW;   // doubles per plane block
  int s;
  if (accMode == 0) s = seg;
  else              s = (seg < nplanes) ? seg : (seg - nplanes);
  double* base = P0g + (size_t)s*planeD;
  const int cnt = kcount[b];
  const int ks = (int)((long long)cnt * seg / nseg);
  const int ke = (int)((long long)cnt * (seg+1) / nseg);
  double* Ab = base + (size_t)b*NP1*WROW;
  gemm_tile(b, TI10[t]*64, TJ10[t]*64, threadIdx.x, Tg, klist, kw, ks, ke, Ab,
            true, accMode != 0, S);
}

// ---------------- K2b (grid 512): fold planes 3..nacc-1 into 0..2 ---------------
// RACE-FREE: each work item owns ONE dst element (plane d<3, batch, row, col-pair)
// and sums ALL its sources d+3, d+6, ... (interior 256x256 only -- all tile writes
// land there; borders live only in planes 0..2, written by prep).
__global__ __launch_bounds__(256) void merge_planes(double* __restrict__ P0g, int nacc)
{
  const size_t per = (size_t)NP1*WROW >> 1;        // 33153 double2 per (plane,batch)
  double2* B = (double2*)P0g;
  const size_t nwork = (size_t)3*NBATCH*256*128;   // dst planes 0..2 x 8 b x 256 r x 128 c2
  for (size_t i = (size_t)blockIdx.x*256 + threadIdx.x; i < nwork;
       i += (size_t)gridDim.x*256) {
    const int c2 = (int)(i & 127);
    size_t t = i >> 7;
    const int rr = (int)(t & 255);
    const int pb = (int)(t >> 8);                  // dst (plane*8 + batch), 0..23
    const int dpl = pb >> 3;                       // dst plane 0..2
    const size_t d = (size_t)pb*per + (size_t)rr*129 + c2;
    double2 a = B[d];
    for (int q = dpl + 3; q < nacc; q += 3) {
      const double2 x = B[d + (size_t)(q - dpl)*8*per];
      a.x += x.x; a.y += x.y;
    }
    B[d] = a;
  }
}

// ---------------- K4a (grid 16, block 768): column-split no-pivot LU factor -----
// BYTE-IDENTICAL to the round-13/14 banked version (282us, passing).
__global__ __launch_bounds__(BDF, 2) void solve_factor(
    double* __restrict__ P0g, const double* __restrict__ P1g, const double* __restrict__ P2g,
    int nplanes,
    const void* __restrict__ c0, const void* __restrict__ c1, const void* __restrict__ c2,
    const float* __restrict__ Jraw,
    int4* __restrict__ klist, double* __restrict__ U11g)
{
  const int b = blockIdx.x >> 1;
  const int h = blockIdx.x & 1;
  const int tid = threadIdx.x;
  double* Pb = P0g + (size_t)b*NP1*WROW;
  const double* Qb = P1g + (size_t)b*NP1*WROW;
  const double* Rb = P2g + (size_t)b*NP1*WROW;
  const bool two   = (nplanes > 1);
  const bool three = (nplanes > 2);
  int* FA = (int*)(klist + (size_t)b*KCAP + FLAGOFF);   // FA[p]: h0 done panel p
  int* FB = FA + 32;                                     // FB[p]: h1 done panel p
  double* U11b = U11g + (size_t)b*17*256;

  __shared__ __align__(16) double pan[NP1+4][NB+2];
  __shared__ double dnv[NB];
  __shared__ __align__(16) double Ub[NB][UBW];

  const float* chi = nullptr; const int* znum = nullptr;
  classify2(c0, c1, c2, chi, znum);
  const float J0 = Jraw[0], J1 = Jraw[1], J2 = Jraw[2], J3 = Jraw[3];

  int p = 0;
  for (int p0 = 0; p0 < NP1; p0 += NB, p++) {
    const int pw  = (NB < NP1 - p0) ? NB : (NP1 - p0);
    const int nr  = NP1 - p0;
    const int nrt = nr - pw;
    const int tc0 = p0 + pw;
    const int tc  = WROW - tc0;                         // even
    const bool first = (p0 == 0);
    int leftCols = (tc >= 4) ? (((tc >> 1) + 1) & ~1) : tc;
    const int clo = (h == 0) ? tc0 : tc0 + leftCols;
    const int chiC = (h == 0) ? tc0 + leftCols : tc0 + tc;
    const int ownCols = chiC - clo;
    if (p > 0) {
      if (tid == 0) {
        while (atomicAdd(&FA[p-1], 0) == 0) __builtin_amdgcn_s_sleep(2);
        while (atomicAdd(&FB[p-1], 0) == 0) __builtin_amdgcn_s_sleep(2);
        __threadfence();
      }
      __syncthreads();
    }
    for (int idx = tid; idx < nr*pw; idx += BDF) {
      int r, c;
      if (pw == NB) { r = idx >> 4; c = idx & 15; } else { r = idx; c = 0; }
      double v;
      if (first) {
        size_t a = (size_t)r*WROW + c;
        v = Pb[a];
        if (two)   v += Qb[a];
        if (three) v += Rb[a];
        if (r == c) {
          int z = znum[b*NATOM + r];
          float Jr = (z == 1) ? J0 : (z == 6) ? J1 : (z == 7) ? J2 : J3;
          v += (double)Jr*(double)Jr - DIAG_SUB;
        }
      } else {
        v = Pb[(size_t)(p0+r)*WROW + p0 + c];
      }
      pan[r][c] = v;
    }
    __syncthreads();
    if (pw == NB) {
      if (tid < NB) {
        double v[NB];
#pragma unroll
        for (int c = 0; c < NB; c++) v[c] = pan[tid][c];
#pragma unroll
        for (int c = 0; c < NB; c++) {
          double piv = __shfl(v[c], c);
          double dinv = 1.0 / piv;
          if (tid == c) dnv[c] = dinv;
          double f = v[c] * dinv;
#pragma unroll
          for (int cc = 0; cc < NB; cc++) {
            if (cc > c) {
              double ucc = __shfl(v[cc], c);
              if (tid > c) v[cc] -= f * ucc;
            }
          }
          if (tid > c) v[c] = f;
        }
#pragma unroll
        for (int c = 0; c < NB; c++) pan[tid][c] = v[c];
      }
    }
    __syncthreads();
    if (pw == NB) {
      if (tid < nrt) {
        const int r = NB + tid;
        double w[NB];
#pragma unroll
        for (int c = 0; c < NB; c++) w[c] = pan[r][c];
#pragma unroll
        for (int c = 0; c < NB; c++) {
          double s = w[c];
#pragma unroll
          for (int c2 = 0; c2 < NB; c2++) if (c2 < c) s -= w[c2] * pan[c2][c];
          w[c] = s * dnv[c];
        }
#pragma unroll
        for (int c = 0; c < NB; c++) pan[r][c] = w[c];
      } else if (tid >= 256 && tid < 256 + ownCols) {
        const int j = clo + (tid - 256);
        double v[NB];
#pragma unroll
        for (int c = 0; c < NB; c++) {
          size_t a = (size_t)(p0+c)*WROW + j;
          double t = Pb[a];
          if (first) {
            if (two)   t += Qb[a];
            if (three) t += Rb[a];
          }
          v[c] = t;
        }
#pragma unroll
        for (int c = 0; c < NB; c++)
#pragma unroll
          for (int r2 = 0; r2 < NB; r2++) if (r2 > c) v[r2] -= pan[r2][c]*v[c];
#pragma unroll
        for (int c = 0; c < NB; c++) {
          Pb[(size_t)(p0+c)*WROW + j] = v[c];
          Ub[c][tid - 256] = v[c];
        }
      } else if (h == 0 && tid >= 512) {
        const int idx = tid - 512;                    // 0..255
        U11b[p*256 + idx] = pan[idx >> 4][idx & 15];
      }
    } else {
      if (h == 0 && tid == 0) U11b[16*256] = pan[0][0];
    }
    __syncthreads();
    if (pw == NB && ownCols > 0 && nrt > 0) {
      const int jp   = tid & 63;
      const int rowg = tid >> 6;                      // 0..11
      if (clo + 2*jp < chiC) {
        const int jrel = (clo - tc0) + 2*jp;          // even
        double va[NB], vb[NB];
#pragma unroll
        for (int c = 0; c < NB; c++) {
          double2 u = *(const double2*)&Ub[c][2*jp];
          va[c] = u.x; vb[c] = u.y;
        }
        auto loadrow = [&](int rr, double2& x0, double2& x1) {
          x0 = make_double2(0.0, 0.0); x1 = x0;
          if (rr < nrt) {
            const int row0 = tc0 + rr;
            const size_t ad = (size_t)row0*WROW + tc0 + jrel;
            x0 = *(const double2*)&Pb[ad];
            if (rr + 1 < nrt) x1 = *(const double2*)&Pb[ad + WROW];
            if (first) {
              if (two) {
                double2 q0 = *(const double2*)&Qb[ad]; x0.x += q0.x; x0.y += q0.y;
                if (rr + 1 < nrt) { double2 q1 = *(const double2*)&Qb[ad + WROW]; x1.x += q1.x; x1.y += q1.y; }
              }
              if (three) {
                double2 r0v = *(const double2*)&Rb[ad]; x0.x += r0v.x; x0.y += r0v.y;
                if (rr + 1 < nrt) { double2 r1v = *(const double2*)&Rb[ad + WROW]; x1.x += r1v.x; x1.y += r1v.y; }
              }
              if (rr == jrel) {
                const int row0g = tc0 + rr;
                if (row0g < NATOM) {
                  int z = znum[b*NATOM + row0g];
                  float Jr = (z == 1) ? J0 : (z == 6) ? J1 : (z == 7) ? J2 : J3;
                  x0.x += (double)Jr*(double)Jr - DIAG_SUB;
                }
                if (rr + 1 < nrt && row0g + 1 < NATOM) {
                  int z = znum[b*NATOM + row0g + 1];
                  float Jr = (z == 1) ? J0 : (z == 6) ? J1 : (z == 7) ? J2 : J3;
                  x1.y += (double)Jr*(double)Jr - DIAG_SUB;
                }
              }
            }
          }
        };
        int rr = 2*rowg;
        double2 a0, a1;
        loadrow(rr, a0, a1);
        while (rr < nrt) {
          const int rn = rr + 24;                     // 12 row-groups x 2 rows
          double2 n0, n1;
          loadrow(rn, n0, n1);
          const double* pr0 = pan[NB + rr];
          const double* pr1 = pan[NB + rr + 1];
#pragma unroll
          for (int m = 0; m < NB/2; m++) {
            double2 l0 = *(const double2*)&pr0[2*m];
            double2 l1 = *(const double2*)&pr1[2*m];
            a0.x -= l0.x*va[2*m] + l0.y*va[2*m+1];
            a0.y -= l0.x*vb[2*m] + l0.y*vb[2*m+1];
            a1.x -= l1.x*va[2*m] + l1.y*va[2*m+1];
            a1.y -= l1.x*vb[2*m] + l1.y*vb[2*m+1];
          }
          const size_t ad = (size_t)(tc0+rr)*WROW + tc0 + jrel;
          *(double2*)&Pb[ad] = a0;
          if (rr + 1 < nrt) *(double2*)&Pb[ad + WROW] = a1;
          a0 = n0; a1 = n1;
          rr = rn;
        }
      }
    }
    __syncthreads();
    if (pw == NB && tid == 0) {
      __threadfence();
      if (h == 0) atomicExch(&FA[p], 1);
      else        atomicExch(&FB[p], 1);
    }
  }
}

// ---------------- K4b (grid 8, block 256): backsolve + outputs ----------------
__global__ __launch_bounds__(BDB) void solve_back(
    double* __restrict__ P0g, const double* __restrict__ U11g,
    const void* __restrict__ c0, const void* __restrict__ c1, const void* __restrict__ c2,
    const float* __restrict__ Jraw, const float* __restrict__ syschg,
    float* __restrict__ out)
{
  const int b = blockIdx.x;
  const int tid = threadIdx.x;
  double* Pb = P0g + (size_t)b*NP1*WROW;
  const double* U11b = U11g + (size_t)b*17*256;

  __shared__ double panb[NB][NB+1];
  __shared__ double xs[NP1];
  __shared__ double red[BDB];

  const float* chi = nullptr; const int* znum = nullptr;
  classify2(c0, c1, c2, chi, znum);
  const double rhsN = (double)syschg[b] * sqrt(90.0474);
  const float J0 = Jraw[0], J1 = Jraw[1], J2 = Jraw[2], J3 = Jraw[3];

  for (int r = tid; r < NP1; r += BDB) xs[r] = Pb[(size_t)r*WROW + 257];
  __syncthreads();
  for (int pb0 = 256; pb0 >= 0; pb0 -= NB) {
    const int w = (pb0 == 256) ? 1 : NB;
    if (w == NB) {
      {
        const int i = tid >> 4, c = tid & 15;
        panb[i][c] = U11b[(pb0 >> 4)*256 + i*16 + c];
      }
      __syncthreads();
      if (tid < NB) {
        double u[NB];
#pragma unroll
        for (int c = 0; c < NB; c++) u[c] = panb[tid][c];
        double y  = xs[pb0 + tid];
        double di = 1.0 / panb[tid][tid];
        double xr = 0.0;
#pragma unroll
        for (int i = NB-1; i >= 0; i--) {
          double xi = y * di;
          xi = __shfl(xi, i);
          if (tid == i) xr = xi;
          if (tid < i)  y -= u[i] * xi;
        }
        xs[pb0 + tid] = xr;
      }
    } else {
      if (tid == 0) xs[256] = xs[256] / U11b[16*256];
    }
    __syncthreads();
    if (tid < pb0) {
      const double* rowp = &Pb[(size_t)tid*WROW + pb0];
      double s = 0.0;
      for (int c = 0; c < w; c++) s += rowp[c]*xs[pb0+c];
      xs[tid] -= s;
    }
    __syncthreads();
  }

  // ---- outputs: q + residual-identity energy ----
  out[b*NATOM + tid] = (float)xs[tid];
  const double lam = xs[NATOM];
  double q  = xs[tid];
  double ch = (double)chi[b*NATOM + tid];
  int z = znum[b*NATOM + tid];
  float Jr = (z == 1) ? J0 : (z == 6) ? J1 : (z == 7) ? J2 : J3;
  red[tid] = q*ch + (double)Jr*(double)Jr*q*q;
  __syncthreads();
  for (int st = BDB/2; st > 0; st >>= 1) {
    if (tid < st) red[tid] += red[tid + st];
    __syncthreads();
  }
  if (tid == 0)
    out[NBATCH*NATOM + b] = (float)(-0.5*(red[0] + lam*rhsN));
}

// ---------------- host launch ----------------
extern "C" void kernel_launch(void* const* d_in, const int* in_sizes, int n_in,
                              void* d_out, int out_size, void* d_ws, size_t ws_size,
                              hipStream_t stream)
{
  int iPos=-1, iCell=-1, iJ=-1, iQ=-1, cand[3]={-1,-1,-1}, nc=0;
  for (int i = 0; i < n_in; i++) {
    int s = in_sizes[i];
    if      (s == 6144) iPos  = i;
    else if (s == 72)   iCell = i;
    else if (s == 4)    iJ    = i;
    else if (s == 8)    iQ    = i;
    else if (s == 2048 && nc < 3) cand[nc++] = i;
  }
  if (!(iPos>=0 && iCell>=0 && iJ>=0 && iQ>=0 && nc>=2)) {
    iPos=iCell=iJ=iQ=-1; nc=0; cand[0]=cand[1]=cand[2]=-1;
    for (int i = 0; i < n_in; i++) {
      int s = in_sizes[i];
      if      (s == 24576) iPos  = i;
      else if (s == 288)   iCell = i;
      else if (s == 16)    iJ    = i;
      else if (s == 32)    iQ    = i;
      else if (s == 8192 && nc < 3) cand[nc++] = i;
    }
  }
  if (!(iPos>=0 && iCell>=0 && iJ>=0 && iQ>=0 && nc>=2)) {
    iPos=0; iCell=1; iJ=3; iQ=4; cand[0]=2; cand[1]=5; cand[2]=6; nc=3;
  }
  if (nc == 2) cand[2] = cand[1];

  const float* pos  = (const float*)d_in[iPos];
  const float* cell = (const float*)d_in[iCell];
  const float* Jraw = (const float*)d_in[iJ];
  const float* sysq = (const float*)d_in[iQ];
  const void*  c0   = d_in[cand[0]];
  const void*  c1   = d_in[cand[1]];
  const void*  c2   = d_in[cand[2]];
  float* out = (float*)d_out;

  // ws: [plane0..planeN-1][Tg][klist][kw][kcount]
  const size_t planeB = (size_t)NBATCH*NP1*WROW*sizeof(double);  // 4,243,584
  const size_t tgB = 2064384, klB = 327680, kwB = 163840;
  const size_t trigAll = tgB + klB + kwB + 64;
  int nacc;                       // accumulation planes allocated
  if      (ws_size >= 12*planeB + trigAll) nacc = 12;  // wide store path
  else if (ws_size >=  6*planeB + trigAll) nacc = 6;   // store path (r14, 542us)
  else if (ws_size >=  3*planeB + trigAll) nacc = 3;   // atomic path (r13)
  else if (ws_size >=  2*planeB + trigAll) nacc = 2;
  else                                     nacc = 1;
  const int nplanes = (nacc >= 3) ? 3 : nacc;          // planes the factor sums
  const int accMode = (nacc >= 6) ? 0 : 1;             // 0 = store, 1 = atomic

  char* ws = (char*)d_ws;
  double*  P0g = (double*)ws;
  double*  P1g = (nacc > 1) ? (double*)(ws + planeB)   : P0g;
  double*  P2g = (nacc > 2) ? (double*)(ws + 2*planeB) : P1g;
  char* trigBase = ws + (size_t)nacc*planeB;
  double2* Tg     = (double2*)trigBase;
  int4*    klist  = (int4*)  (trigBase + tgB);
  double*  kwa    = (double*)(trigBase + tgB + klB);
  int*     kcount = (int*)   (trigBase + tgB + klB + kwB);
  double*  U11g   = (double*)trigBase;   // Tg region dead after build_A; 278KB << 2MB

  const int nseg = (accMode == 0) ? nacc : 2*nplanes;

  hipLaunchKernelGGL(zero_planes,  dim3(512),       dim3(256), 0, stream,
                     P0g, klist, (accMode == 1) ? nplanes : 0);
  hipLaunchKernelGGL(prep,         dim3(NBATCH),    dim3(256), 0, stream,
                     pos, cell, Tg, klist, kwa, kcount, c0, c1, c2, sysq,
                     P0g, P1g, P2g, nplanes);
  hipLaunchKernelGGL(build_A_gemm, dim3(80*nseg),   dim3(256), 0, stream,
                     Tg, klist, kwa, kcount, P0g, nplanes, accMode, nseg);
  if (accMode == 0)
    hipLaunchKernelGGL(merge_planes, dim3(512),     dim3(256), 0, stream, P0g, nacc);
  hipLaunchKernelGGL(solve_factor, dim3(2*NBATCH),  dim3(BDF), 0, stream,
                     P0g, P1g, P2g, nplanes, c0, c1, c2, Jraw, klist, U11g);
  hipLaunchKernelGGL(solve_back,   dim3(NBATCH),    dim3(BDB), 0, stream,
                     P0g, U11g, c0, c1, c2, Jraw, sysq, out);
}

// Round 16
// 524.040 us; speedup vs baseline: 1.3201x; 1.0182x over previous
//
#include <hip/hip_runtime.h>
#include <math.h>

#define NBATCH 8
#define NATOM  256
#define NP1    257
#define WROW   258
#define TOTALK 9261
#define KCAP   2560
#define KC     16
#define NB     16
#define UBW    124
#define BDF    768
#define FLAGOFF 2528          /* int4 slot where per-batch flags live in klist tail */
#define SLOTMAX 2500          /* prep never writes k-entries at/above this slot */

#define TWO_PI_D 6.283185307179586
#define DIAG_SUB 0.7978845608028654   /* 2/sqrt(2*pi) */

__device__ __constant__ int TI10[10] = {0,0,0,0,1,1,1,2,2,3};
__device__ __constant__ int TJ10[10] = {0,1,2,3,1,2,3,2,3,3};

struct GemmSh {
  int4   kn[KC];
  double kw[KC];
  double cI[KC][64], sI[KC][64];
  double cJ[KC][64], sJ[KC][64];
};

// HW fp64 atomic add (gfx90a+/gfx950); CAS fallback if builtin missing.
__device__ __forceinline__ void atomAddD(double* p, double v) {
#if defined(__has_builtin)
#if __has_builtin(__builtin_amdgcn_global_atomic_fadd_f64)
  __builtin_amdgcn_global_atomic_fadd_f64(p, v);
  return;
#endif
#endif
  unsigned long long* u = (unsigned long long*)p;
  unsigned long long old = *u, assumed;
  do {
    assumed = old;
    old = atomicCAS(u, assumed,
                    (unsigned long long)__double_as_longlong(
                        v + __longlong_as_double((long long)assumed)));
  } while (old != assumed);
}

__device__ __forceinline__ void classify2(const void* c0, const void* c1, const void* c2,
                                          const float*& chi, const int*& znum)
{
  const void* cands[3] = {c0, c1, c2};
  int got = 0;
  for (int i = 0; i < 3; i++) {
    unsigned uu = ((const unsigned*)cands[i])[0];
    if (uu == 0u) continue;                                      // batch
    else if (uu < 16u) { znum = (const int*)cands[i]; got |= 1; }// z in {1,6,7,8}
    else               { chi  = (const float*)cands[i]; got |= 2; }
  }
  if (got != 3) { chi = (const float*)c0; znum = (const int*)c1; }
}

// ---------------- K0 (grid 512, ATOMIC PATH ONLY): zero A-planes -----------------
__global__ __launch_bounds__(256) void zero_planes(
    double* __restrict__ P0g, int nzero)
{
  const size_t npair = (size_t)nzero * NBATCH * ((NP1*WROW) >> 1);
  double2* Z = (double2*)P0g;   // planes are contiguous
  const double2 z = make_double2(0.0, 0.0);
  for (size_t i = (size_t)blockIdx.x*256 + threadIdx.x; i < npair;
       i += (size_t)gridDim.x*256)
    Z[i] = z;
}

// ---------------- K1 (grid 8): flags + trig tables + k-list + aug borders --------
__global__ __launch_bounds__(256) void prep(
    const float* __restrict__ pos, const float* __restrict__ cell,
    double2* __restrict__ Tg, int4* __restrict__ klist,
    double* __restrict__ kw, int* __restrict__ kcount,
    const void* __restrict__ c0, const void* __restrict__ c1, const void* __restrict__ c2,
    const float* __restrict__ syschg,
    double* __restrict__ P0g, double* __restrict__ P1g, double* __restrict__ P2g,
    int nplanes)
{
  const int b = blockIdx.x;
  const int tid = threadIdx.x;
  __shared__ double ivs[9];
  __shared__ double prefs;
  __shared__ int cnt;
  if (tid < 32)   // zero this batch's factor sync flags (was zero_planes' job)
    klist[(size_t)b*KCAP + FLAGOFF + tid] = make_int4(0, 0, 0, 0);
  if (tid == 0) {
    double c[9];
#pragma unroll
    for (int i = 0; i < 9; i++) c[i] = (double)cell[b*9+i];
    double det = c[0]*(c[4]*c[8]-c[5]*c[7]) - c[1]*(c[3]*c[8]-c[5]*c[6])
               + c[2]*(c[3]*c[7]-c[4]*c[6]);
    double idet = 1.0/det;
    ivs[0]=(c[4]*c[8]-c[5]*c[7])*idet; ivs[1]=(c[2]*c[7]-c[1]*c[8])*idet; ivs[2]=(c[1]*c[5]-c[2]*c[4])*idet;
    ivs[3]=(c[5]*c[6]-c[3]*c[8])*idet; ivs[4]=(c[0]*c[8]-c[2]*c[6])*idet; ivs[5]=(c[2]*c[3]-c[0]*c[5])*idet;
    ivs[6]=(c[3]*c[7]-c[4]*c[6])*idet; ivs[7]=(c[1]*c[6]-c[0]*c[7])*idet; ivs[8]=(c[0]*c[4]-c[1]*c[3])*idet;
    prefs = 2.0*TWO_PI_D/fabs(det);
    cnt = 0;
  }
  __syncthreads();
  {
    const int a = tid;
    double x = (double)pos[((size_t)b*NATOM+a)*3+0];
    double y = (double)pos[((size_t)b*NATOM+a)*3+1];
    double z = (double)pos[((size_t)b*NATOM+a)*3+2];
    double u[3];
    u[0] = TWO_PI_D*(ivs[0]*x + ivs[3]*y + ivs[6]*z);
    u[1] = TWO_PI_D*(ivs[1]*x + ivs[4]*y + ivs[7]*z);
    u[2] = TWO_PI_D*(ivs[2]*x + ivs[5]*y + ivs[8]*z);
#pragma unroll
    for (int d = 0; d < 3; d++) {
      double2* T = Tg + (size_t)((b*3 + d)*21)*256;
      double c1 = cos(u[d]);
      double s1 = sin(u[d]);
      T[10*256 + a] = make_double2(1.0, 0.0);
      T[11*256 + a] = make_double2(c1,  s1);
      T[ 9*256 + a] = make_double2(c1, -s1);
      double cp = c1, sp = s1;
      for (int n = 2; n <= 10; n++) {
        double cn = cp*c1 - sp*s1;
        double sn = sp*c1 + cp*s1;
        cp = cn; sp = sn;
        T[(10+n)*256 + a] = make_double2(cp,  sp);
        T[(10-n)*256 + a] = make_double2(cp, -sp);
      }
    }
  }
  const double ksqmax = (TWO_PI_D/1.5)*(TWO_PI_D/1.5);
  for (int m = tid; m < TOTALK; m += 256) {
    int n1 = m/441 - 10;
    int n2 = (m/21)%21 - 10;
    int n3 = m%21 - 10;
    bool half = (n1 > 0) || (n1 == 0 && (n2 > 0 || (n2 == 0 && n3 > 0)));
    if (!half) continue;
    double d1 = n1, d2 = n2, d3 = n3;
    double kx = TWO_PI_D*(ivs[0]*d1 + ivs[1]*d2 + ivs[2]*d3);
    double ky = TWO_PI_D*(ivs[3]*d1 + ivs[4]*d2 + ivs[5]*d3);
    double kz = TWO_PI_D*(ivs[6]*d1 + ivs[7]*d2 + ivs[8]*d3);
    double k2 = kx*kx + ky*ky + kz*kz;
    if (k2 > 1e-10 && k2 < ksqmax) {
      double w = 2.0 * prefs * exp(-0.5*k2) / k2;
      int slot = atomicAdd(&cnt, 1);
      if (slot < SLOTMAX) {               // protect flag region (cnt ~2100 in practice)
        klist[b*KCAP + slot] = make_int4(n1, n2, n3, 0);
        kw[b*KCAP + slot] = w;
      }
    }
  }
  __syncthreads();   // k-list complete before kcount
  // aug borders: P0 real values; P1/P2 borders zeroed here (store path relies on it)
  {
    const float* chi = nullptr; const int* znum = nullptr;
    classify2(c0, c1, c2, chi, znum);
    double* P0b = P0g + (size_t)b*NP1*WROW;
    double* P1b = P1g + (size_t)b*NP1*WROW;
    double* P2b = P2g + (size_t)b*NP1*WROW;
    for (int i = tid; i < NATOM; i += 256) {
      P0b[(size_t)NATOM*WROW + i] = 1.0;
      P0b[(size_t)i*WROW + NATOM] = 1.0;
      P0b[(size_t)i*WROW + 257]   = -(double)chi[b*NATOM + i];
      if (nplanes > 1) {
        P1b[(size_t)NATOM*WROW + i] = 0.0;
        P1b[(size_t)i*WROW + NATOM] = 0.0;
        P1b[(size_t)i*WROW + 257]   = 0.0;
      }
      if (nplanes > 2) {
        P2b[(size_t)NATOM*WROW + i] = 0.0;
        P2b[(size_t)i*WROW + NATOM] = 0.0;
        P2b[(size_t)i*WROW + 257]   = 0.0;
      }
    }
    if (tid == 0) {
      P0b[(size_t)NATOM*WROW + NATOM] = 0.0;
      P0b[(size_t)NATOM*WROW + 257]   = (double)syschg[b]*sqrt(90.0474);
      if (nplanes > 1) {
        P1b[(size_t)NATOM*WROW + NATOM] = 0.0;
        P1b[(size_t)NATOM*WROW + 257]   = 0.0;
      }
      if (nplanes > 2) {
        P2b[(size_t)NATOM*WROW + NATOM] = 0.0;
        P2b[(size_t)NATOM*WROW + 257]   = 0.0;
      }
      kcount[b] = (cnt < SLOTMAX) ? cnt : SLOTMAX;
    }
  }
}

// ---------------- fp64 tile GEMM into a plane (stores or atomic-accumulate) -----
__device__ void gemm_tile(int b, int ti, int tj, int tid,
                          const double2* __restrict__ Tg,
                          const int4* __restrict__ klist,
                          const double* __restrict__ kw, int ks, int ke,
                          double* __restrict__ Ab, bool mirror, bool useAtomic,
                          GemmSh& S)
{
  const int tx = tid & 15, ty = tid >> 4;
  const int ro = ty << 2, co = tx << 2;
  double acc[16];
#pragma unroll
  for (int i = 0; i < 16; i++) acc[i] = 0.0;

  for (int k0 = ks; k0 < ke; k0 += KC) {
    if (tid < KC) {
      int kk = k0 + tid;
      if (kk < ke) { S.kn[tid] = klist[b*KCAP + kk]; S.kw[tid] = kw[b*KCAP + kk]; }
      else         { S.kn[tid] = make_int4(0,0,0,0); S.kw[tid] = 0.0; }
    }
    __syncthreads();
#pragma unroll
    for (int p = 0; p < 8; p++) {
      int idx = p*256 + tid;
      int a    = idx & 63;
      int kk   = (idx >> 6) & (KC-1);
      int side = idx >> 10;
      int atom = ((side == 0) ? ti : tj) + a;
      int4 nn = S.kn[kk];
      double2 t1 = Tg[(size_t)((b*3+0)*21 + (nn.x+10))*256 + atom];
      double2 t2 = Tg[(size_t)((b*3+1)*21 + (nn.y+10))*256 + atom];
      double2 t3 = Tg[(size_t)((b*3+2)*21 + (nn.z+10))*256 + atom];
      double ex = t1.x*t2.x - t1.y*t2.y;
      double ey = t1.x*t2.y + t1.y*t2.x;
      double cx = ex*t3.x - ey*t3.y;
      double cy = ex*t3.y + ey*t3.x;
      if (side == 0) { double w = S.kw[kk]; S.cI[kk][a] = w*cx; S.sI[kk][a] = w*cy; }
      else           { S.cJ[kk][a] = cx; S.sJ[kk][a] = cy; }
    }
    __syncthreads();
#pragma unroll
    for (int kk = 0; kk < KC; kk++) {
      double ci[4], si[4], cj[4], sj[4];
#pragma unroll
      for (int r = 0; r < 2; r++) {
        double2 v0 = *(const double2*)&S.cI[kk][ro + 2*r];
        ci[2*r] = v0.x; ci[2*r+1] = v0.y;
        double2 v1 = *(const double2*)&S.sI[kk][ro + 2*r];
        si[2*r] = v1.x; si[2*r+1] = v1.y;
        double2 v2 = *(const double2*)&S.cJ[kk][co + 2*r];
        cj[2*r] = v2.x; cj[2*r+1] = v2.y;
        double2 v3 = *(const double2*)&S.sJ[kk][co + 2*r];
        sj[2*r] = v3.x; sj[2*r+1] = v3.y;
      }
#pragma unroll
      for (int r = 0; r < 4; r++)
#pragma unroll
        for (int c = 0; c < 4; c++)
          acc[r*4+c] += ci[r]*cj[c] + si[r]*sj[c];
    }
    __syncthreads();
  }
#pragma unroll
  for (int r = 0; r < 4; r++) {
#pragma unroll
    for (int c = 0; c < 4; c++) {
      int gr = ti + ro + r, gc = tj + co + c;
      double v = acc[r*4+c];
      if (useAtomic) {
        atomAddD(&Ab[(size_t)gr*WROW + gc], v);
        if (mirror && ti != tj) atomAddD(&Ab[(size_t)gc*WROW + gr], v);
      } else {
        Ab[(size_t)gr*WROW + gc] = v;
        if (mirror && ti != tj) Ab[(size_t)gc*WROW + gr] = v;
      }
    }
  }
}

// ---------------- K2 (grid 80*nseg): tiles x batches x k-segments ----------------
__global__ __launch_bounds__(256) void build_A_gemm(
    const double2* __restrict__ Tg, const int4* __restrict__ klist,
    const double* __restrict__ kw, const int* __restrict__ kcount,
    double* __restrict__ P0g, int nplanes, int accMode, int nseg)
{
  __shared__ GemmSh S;
  const int u = blockIdx.x;
  const int seg = u / 80;
  const int r = u - seg*80;
  const int b = r / 10;
  const int t = r - b*10;
  const size_t planeD = (size_t)NBATCH*NP1*WROW;   // doubles per plane block
  int s;
  if (accMode == 0) s = seg;
  else              s = (seg < nplanes) ? seg : (seg - nplanes);
  double* base = P0g + (size_t)s*planeD;
  const int cnt = kcount[b];
  const int ks = (int)((long long)cnt * seg / nseg);
  const int ke = (int)((long long)cnt * (seg+1) / nseg);
  double* Ab = base + (size_t)b*NP1*WROW;
  gemm_tile(b, TI10[t]*64, TJ10[t]*64, threadIdx.x, Tg, klist, kw, ks, ke, Ab,
            true, accMode != 0, S);
}

// ---------------- K2b (grid 512): fold planes 3..nacc-1 into 0..2 ---------------
__global__ __launch_bounds__(256) void merge_planes(double* __restrict__ P0g, int nacc)
{
  const size_t per = (size_t)NP1*WROW >> 1;        // 33153 double2 per (plane,batch)
  double2* B = (double2*)P0g;
  const size_t nwork = (size_t)3*NBATCH*256*128;   // dst planes 0..2 x 8 b x 256 r x 128 c2
  for (size_t i = (size_t)blockIdx.x*256 + threadIdx.x; i < nwork;
       i += (size_t)gridDim.x*256) {
    const int c2 = (int)(i & 127);
    size_t t = i >> 7;
    const int rr = (int)(t & 255);
    const int pb = (int)(t >> 8);                  // dst (plane*8 + batch), 0..23
    const int dpl = pb >> 3;                       // dst plane 0..2
    const size_t d = (size_t)pb*per + (size_t)rr*129 + c2;
    double2 a = B[d];
    for (int q = dpl + 3; q < nacc; q += 3) {
      const double2 x = B[d + (size_t)(q - dpl)*8*per];
      a.x += x.x; a.y += x.y;
    }
    B[d] = a;
  }
}

// ---------------- K4 (grid 16, block 768): column-split LU factor + fused backsolve
// Factor part BYTE-IDENTICAL to r13/14/15 (282us, passing). After the p-loop, the
// p=16 barrier has already acquired FA[15]/FB[15] -> ALL of h1's factor writes are
// visible to h0; h0 runs the backsolve + outputs inline (h1 exits). Removes the
// separate solve_back launch and starts each batch's backsolve the moment its own
// factor completes.
__global__ __launch_bounds__(BDF, 2) void solve_factor(
    double* __restrict__ P0g, const double* __restrict__ P1g, const double* __restrict__ P2g,
    int nplanes,
    const void* __restrict__ c0, const void* __restrict__ c1, const void* __restrict__ c2,
    const float* __restrict__ Jraw, const float* __restrict__ syschg,
    int4* __restrict__ klist, double* __restrict__ U11g, float* __restrict__ out)
{
  const int b = blockIdx.x >> 1;
  const int h = blockIdx.x & 1;
  const int tid = threadIdx.x;
  double* Pb = P0g + (size_t)b*NP1*WROW;
  const double* Qb = P1g + (size_t)b*NP1*WROW;
  const double* Rb = P2g + (size_t)b*NP1*WROW;
  const bool two   = (nplanes > 1);
  const bool three = (nplanes > 2);
  int* FA = (int*)(klist + (size_t)b*KCAP + FLAGOFF);   // FA[p]: h0 done panel p
  int* FB = FA + 32;                                     // FB[p]: h1 done panel p
  double* U11b = U11g + (size_t)b*17*256;

  __shared__ __align__(16) double pan[NP1+4][NB+2];
  __shared__ double dnv[NB];
  __shared__ __align__(16) double Ub[NB][UBW];
  __shared__ double xs[NP1];
  __shared__ double red[256];

  const float* chi = nullptr; const int* znum = nullptr;
  classify2(c0, c1, c2, chi, znum);
  const float J0 = Jraw[0], J1 = Jraw[1], J2 = Jraw[2], J3 = Jraw[3];

  int p = 0;
  for (int p0 = 0; p0 < NP1; p0 += NB, p++) {
    const int pw  = (NB < NP1 - p0) ? NB : (NP1 - p0);
    const int nr  = NP1 - p0;
    const int nrt = nr - pw;
    const int tc0 = p0 + pw;
    const int tc  = WROW - tc0;                         // even
    const bool first = (p0 == 0);
    int leftCols = (tc >= 4) ? (((tc >> 1) + 1) & ~1) : tc;
    const int clo = (h == 0) ? tc0 : tc0 + leftCols;
    const int chiC = (h == 0) ? tc0 + leftCols : tc0 + tc;
    const int ownCols = chiC - clo;
    if (p > 0) {
      if (tid == 0) {
        while (atomicAdd(&FA[p-1], 0) == 0) __builtin_amdgcn_s_sleep(2);
        while (atomicAdd(&FB[p-1], 0) == 0) __builtin_amdgcn_s_sleep(2);
        __threadfence();
      }
      __syncthreads();
    }
    for (int idx = tid; idx < nr*pw; idx += BDF) {
      int r, c;
      if (pw == NB) { r = idx >> 4; c = idx & 15; } else { r = idx; c = 0; }
      double v;
      if (first) {
        size_t a = (size_t)r*WROW + c;
        v = Pb[a];
        if (two)   v += Qb[a];
        if (three) v += Rb[a];
        if (r == c) {
          int z = znum[b*NATOM + r];
          float Jr = (z == 1) ? J0 : (z == 6) ? J1 : (z == 7) ? J2 : J3;
          v += (double)Jr*(double)Jr - DIAG_SUB;
        }
      } else {
        v = Pb[(size_t)(p0+r)*WROW + p0 + c];
      }
      pan[r][c] = v;
    }
    __syncthreads();
    if (pw == NB) {
      if (tid < NB) {
        double v[NB];
#pragma unroll
        for (int c = 0; c < NB; c++) v[c] = pan[tid][c];
#pragma unroll
        for (int c = 0; c < NB; c++) {
          double piv = __shfl(v[c], c);
          double dinv = 1.0 / piv;
          if (tid == c) dnv[c] = dinv;
          double f = v[c] * dinv;
#pragma unroll
          for (int cc = 0; cc < NB; cc++) {
            if (cc > c) {
              double ucc = __shfl(v[cc], c);
              if (tid > c) v[cc] -= f * ucc;
            }
          }
          if (tid > c) v[c] = f;
        }
#pragma unroll
        for (int c = 0; c < NB; c++) pan[tid][c] = v[c];
      }
    }
    __syncthreads();
    if (pw == NB) {
      if (tid < nrt) {
        const int r = NB + tid;
        double w[NB];
#pragma unroll
        for (int c = 0; c < NB; c++) w[c] = pan[r][c];
#pragma unroll
        for (int c = 0; c < NB; c++) {
          double s = w[c];
#pragma unroll
          for (int c2 = 0; c2 < NB; c2++) if (c2 < c) s -= w[c2] * pan[c2][c];
          w[c] = s * dnv[c];
        }
#pragma unroll
        for (int c = 0; c < NB; c++) pan[r][c] = w[c];
      } else if (tid >= 256 && tid < 256 + ownCols) {
        const int j = clo + (tid - 256);
        double v[NB];
#pragma unroll
        for (int c = 0; c < NB; c++) {
          size_t a = (size_t)(p0+c)*WROW + j;
          double t = Pb[a];
          if (first) {
            if (two)   t += Qb[a];
            if (three) t += Rb[a];
          }
          v[c] = t;
        }
#pragma unroll
        for (int c = 0; c < NB; c++)
#pragma unroll
          for (int r2 = 0; r2 < NB; r2++) if (r2 > c) v[r2] -= pan[r2][c]*v[c];
#pragma unroll
        for (int c = 0; c < NB; c++) {
          Pb[(size_t)(p0+c)*WROW + j] = v[c];
          Ub[c][tid - 256] = v[c];
        }
      } else if (h == 0 && tid >= 512) {
        const int idx = tid - 512;                    // 0..255
        U11b[p*256 + idx] = pan[idx >> 4][idx & 15];
      }
    } else {
      if (h == 0 && tid == 0) U11b[16*256] = pan[0][0];
    }
    __syncthreads();
    if (pw == NB && ownCols > 0 && nrt > 0) {
      const int jp   = tid & 63;
      const int rowg = tid >> 6;                      // 0..11
      if (clo + 2*jp < chiC) {
        const int jrel = (clo - tc0) + 2*jp;          // even
        double va[NB], vb[NB];
#pragma unroll
        for (int c = 0; c < NB; c++) {
          double2 u = *(const double2*)&Ub[c][2*jp];
          va[c] = u.x; vb[c] = u.y;
        }
        auto loadrow = [&](int rr, double2& x0, double2& x1) {
          x0 = make_double2(0.0, 0.0); x1 = x0;
          if (rr < nrt) {
            const int row0 = tc0 + rr;
            const size_t ad = (size_t)row0*WROW + tc0 + jrel;
            x0 = *(const double2*)&Pb[ad];
            if (rr + 1 < nrt) x1 = *(const double2*)&Pb[ad + WROW];
            if (first) {
              if (two) {
                double2 q0 = *(const double2*)&Qb[ad]; x0.x += q0.x; x0.y += q0.y;
                if (rr + 1 < nrt) { double2 q1 = *(const double2*)&Qb[ad + WROW]; x1.x += q1.x; x1.y += q1.y; }
              }
              if (three) {
                double2 r0v = *(const double2*)&Rb[ad]; x0.x += r0v.x; x0.y += r0v.y;
                if (rr + 1 < nrt) { double2 r1v = *(const double2*)&Rb[ad + WROW]; x1.x += r1v.x; x1.y += r1v.y; }
              }
              if (rr == jrel) {
                const int row0g = tc0 + rr;
                if (row0g < NATOM) {
                  int z = znum[b*NATOM + row0g];
                  float Jr = (z == 1) ? J0 : (z == 6) ? J1 : (z == 7) ? J2 : J3;
                  x0.x += (double)Jr*(double)Jr - DIAG_SUB;
                }
                if (rr + 1 < nrt && row0g + 1 < NATOM) {
                  int z = znum[b*NATOM + row0g + 1];
                  float Jr = (z == 1) ? J0 : (z == 6) ? J1 : (z == 7) ? J2 : J3;
                  x1.y += (double)Jr*(double)Jr - DIAG_SUB;
                }
              }
            }
          }
        };
        int rr = 2*rowg;
        double2 a0, a1;
        loadrow(rr, a0, a1);
        while (rr < nrt) {
          const int rn = rr + 24;                     // 12 row-groups x 2 rows
          double2 n0, n1;
          loadrow(rn, n0, n1);
          const double* pr0 = pan[NB + rr];
          const double* pr1 = pan[NB + rr + 1];
#pragma unroll
          for (int m = 0; m < NB/2; m++) {
            double2 l0 = *(const double2*)&pr0[2*m];
            double2 l1 = *(const double2*)&pr1[2*m];
            a0.x -= l0.x*va[2*m] + l0.y*va[2*m+1];
            a0.y -= l0.x*vb[2*m] + l0.y*vb[2*m+1];
            a1.x -= l1.x*va[2*m] + l1.y*va[2*m+1];
            a1.y -= l1.x*vb[2*m] + l1.y*vb[2*m+1];
          }
          const size_t ad = (size_t)(tc0+rr)*WROW + tc0 + jrel;
          *(double2*)&Pb[ad] = a0;
          if (rr + 1 < nrt) *(double2*)&Pb[ad + WROW] = a1;
          a0 = n0; a1 = n1;
          rr = rn;
        }
      }
    }
    __syncthreads();
    if (pw == NB && tid == 0) {
      __threadfence();
      if (h == 0) atomicExch(&FA[p], 1);
      else        atomicExch(&FB[p], 1);
    }
  }

  // ---- fused backsolve + outputs (h0 only; all h1 writes acquired at p=16) ----
  if (h == 1) return;
  const double rhsN = (double)syschg[b] * sqrt(90.0474);
  for (int r = tid; r < NP1; r += BDF) xs[r] = Pb[(size_t)r*WROW + 257];
  __syncthreads();
  for (int pb0 = 256; pb0 >= 0; pb0 -= NB) {
    const int w = (pb0 == 256) ? 1 : NB;
    if (w == NB) {
      if (tid < 256) {
        const int i = tid >> 4, c = tid & 15;
        pan[i][c] = U11b[(pb0 >> 4)*256 + i*16 + c];
      }
      __syncthreads();
      if (tid < NB) {
        double u[NB];
#pragma unroll
        for (int c = 0; c < NB; c++) u[c] = pan[tid][c];
        double y  = xs[pb0 + tid];
        double di = 1.0 / pan[tid][tid];
        double xr = 0.0;
#pragma unroll
        for (int i = NB-1; i >= 0; i--) {
          double xi = y * di;
          xi = __shfl(xi, i);
          if (tid == i) xr = xi;
          if (tid < i)  y -= u[i] * xi;
        }
        xs[pb0 + tid] = xr;
      }
    } else {
      if (tid == 0) xs[256] = xs[256] / U11b[16*256];
    }
    __syncthreads();
    if (tid < pb0) {
      const double* rowp = &Pb[(size_t)tid*WROW + pb0];
      double s = 0.0;
      for (int c = 0; c < w; c++) s += rowp[c]*xs[pb0+c];
      xs[tid] -= s;
    }
    __syncthreads();
  }
  // outputs: q + residual-identity energy
  const double lam = xs[NATOM];
  double contrib = 0.0;
  if (tid < NATOM) {
    out[b*NATOM + tid] = (float)xs[tid];
    double q  = xs[tid];
    double ch = (double)chi[b*NATOM + tid];
    int z = znum[b*NATOM + tid];
    float Jr = (z == 1) ? J0 : (z == 6) ? J1 : (z == 7) ? J2 : J3;
    contrib = q*ch + (double)Jr*(double)Jr*q*q;
  }
  if (tid < 256) red[tid] = contrib;
  __syncthreads();
  for (int st = 128; st > 0; st >>= 1) {
    if (tid < st) red[tid] += red[tid + st];
    __syncthreads();
  }
  if (tid == 0)
    out[NBATCH*NATOM + b] = (float)(-0.5*(red[0] + lam*rhsN));
}

// ---------------- host launch ----------------
extern "C" void kernel_launch(void* const* d_in, const int* in_sizes, int n_in,
                              void* d_out, int out_size, void* d_ws, size_t ws_size,
                              hipStream_t stream)
{
  int iPos=-1, iCell=-1, iJ=-1, iQ=-1, cand[3]={-1,-1,-1}, nc=0;
  for (int i = 0; i < n_in; i++) {
    int s = in_sizes[i];
    if      (s == 6144) iPos  = i;
    else if (s == 72)   iCell = i;
    else if (s == 4)    iJ    = i;
    else if (s == 8)    iQ    = i;
    else if (s == 2048 && nc < 3) cand[nc++] = i;
  }
  if (!(iPos>=0 && iCell>=0 && iJ>=0 && iQ>=0 && nc>=2)) {
    iPos=iCell=iJ=iQ=-1; nc=0; cand[0]=cand[1]=cand[2]=-1;
    for (int i = 0; i < n_in; i++) {
      int s = in_sizes[i];
      if      (s == 24576) iPos  = i;
      else if (s == 288)   iCell = i;
      else if (s == 16)    iJ    = i;
      else if (s == 32)    iQ    = i;
      else if (s == 8192 && nc < 3) cand[nc++] = i;
    }
  }
  if (!(iPos>=0 && iCell>=0 && iJ>=0 && iQ>=0 && nc>=2)) {
    iPos=0; iCell=1; iJ=3; iQ=4; cand[0]=2; cand[1]=5; cand[2]=6; nc=3;
  }
  if (nc == 2) cand[2] = cand[1];

  const float* pos  = (const float*)d_in[iPos];
  const float* cell = (const float*)d_in[iCell];
  const float* Jraw = (const float*)d_in[iJ];
  const float* sysq = (const float*)d_in[iQ];
  const void*  c0   = d_in[cand[0]];
  const void*  c1   = d_in[cand[1]];
  const void*  c2   = d_in[cand[2]];
  float* out = (float*)d_out;

  // ws: [plane0..planeN-1][Tg][klist][kw][kcount]
  const size_t planeB = (size_t)NBATCH*NP1*WROW*sizeof(double);  // 4,243,584
  const size_t tgB = 2064384, klB = 327680, kwB = 163840;
  const size_t trigAll = tgB + klB + kwB + 64;
  int nacc;                       // accumulation planes allocated
  if      (ws_size >= 12*planeB + trigAll) nacc = 12;  // wide store path
  else if (ws_size >=  6*planeB + trigAll) nacc = 6;   // store path (r14/r15)
  else if (ws_size >=  3*planeB + trigAll) nacc = 3;   // atomic path (r13)
  else if (ws_size >=  2*planeB + trigAll) nacc = 2;
  else                                     nacc = 1;
  const int nplanes = (nacc >= 3) ? 3 : nacc;          // planes the factor sums
  const int accMode = (nacc >= 6) ? 0 : 1;             // 0 = store, 1 = atomic

  char* ws = (char*)d_ws;
  double*  P0g = (double*)ws;
  double*  P1g = (nacc > 1) ? (double*)(ws + planeB)   : P0g;
  double*  P2g = (nacc > 2) ? (double*)(ws + 2*planeB) : P1g;
  char* trigBase = ws + (size_t)nacc*planeB;
  double2* Tg     = (double2*)trigBase;
  int4*    klist  = (int4*)  (trigBase + tgB);
  double*  kwa    = (double*)(trigBase + tgB + klB);
  int*     kcount = (int*)   (trigBase + tgB + klB + kwB);
  double*  U11g   = (double*)trigBase;   // Tg region dead after build_A; 278KB << 2MB

  const int nseg = (accMode == 0) ? nacc : 2*nplanes;

  if (accMode == 1)
    hipLaunchKernelGGL(zero_planes, dim3(512),     dim3(256), 0, stream,
                       P0g, nplanes);
  hipLaunchKernelGGL(prep,         dim3(NBATCH),   dim3(256), 0, stream,
                     pos, cell, Tg, klist, kwa, kcount, c0, c1, c2, sysq,
                     P0g, P1g, P2g, nplanes);
  hipLaunchKernelGGL(build_A_gemm, dim3(80*nseg),  dim3(256), 0, stream,
                     Tg, klist, kwa, kcount, P0g, nplanes, accMode, nseg);
  if (accMode == 0)
    hipLaunchKernelGGL(merge_planes, dim3(512),    dim3(256), 0, stream, P0g, nacc);
  hipLaunchKernelGGL(solve_factor, dim3(2*NBATCH), dim3(BDF), 0, stream,
                     P0g, P1g, P2g, nplanes, c0, c1, c2, Jraw, sysq,
                     klist, U11g, out);
}